// Round 1
// baseline (2039.590 us; speedup 1.0000x reference)
//
#include <hip/hip_runtime.h>
#include <hip/hip_bf16.h>
#include <math.h>

#define NN 50000
#define NE 800000
#define HD 128
#define EPS_BN 1e-5f

// ---------------- CSR build ----------------
__global__ void count_edges(const int* __restrict__ col, int* __restrict__ counts, int E) {
    int e = blockIdx.x * 256 + threadIdx.x;
    if (e >= E) return;
    atomicAdd(&counts[col[e]], 1);
}

__global__ void dis_kernel(const int* __restrict__ counts, float* __restrict__ dis, int N) {
    int i = blockIdx.x * 256 + threadIdx.x;
    if (i >= N) return;
    int c = counts[i];
    dis[i] = (c > 0) ? rsqrtf((float)c) : 0.0f;
}

__global__ __launch_bounds__(1024) void scan_kernel(const int* __restrict__ counts,
                                                    int* __restrict__ offsets, int n) {
    __shared__ int wsum[16];
    int tid = threadIdx.x;
    int lane = tid & 63;
    int w = tid >> 6;
    int carry = 0;
    for (int base = 0; base < n; base += 1024) {
        int i = base + tid;
        int v = (i < n) ? counts[i] : 0;
        int x = v;
        #pragma unroll
        for (int o = 1; o < 64; o <<= 1) {
            int t = __shfl_up(x, o, 64);
            if (lane >= o) x += t;
        }
        if (lane == 63) wsum[w] = x;
        __syncthreads();
        if (w == 0 && lane < 16) {
            int y = wsum[lane];
            #pragma unroll
            for (int o = 1; o < 16; o <<= 1) {
                int t = __shfl_up(y, o, 64);
                if (lane >= o) y += t;
            }
            wsum[lane] = y;
        }
        __syncthreads();
        int wpre = (w > 0) ? wsum[w - 1] : 0;
        int incl = carry + wpre + x;
        if (i < n) offsets[i] = incl - v;  // exclusive
        carry += wsum[15];
        __syncthreads();
    }
    if (tid == 0) offsets[n] = carry;
}

__global__ void scatter_edges(const int* __restrict__ row, const int* __restrict__ col,
                              const float* __restrict__ dis, const int* __restrict__ offsets,
                              int* __restrict__ cursor, int* __restrict__ row_sorted,
                              float* __restrict__ ew_sorted, int E) {
    int e = blockIdx.x * 256 + threadIdx.x;
    if (e >= E) return;
    int c = col[e], r = row[e];
    int pos = offsets[c] + atomicAdd(&cursor[c], 1);
    row_sorted[pos] = r;
    ew_sorted[pos] = dis[c] * dis[r];
}

// ---------------- Graph propagation (CSR gather) ----------------
__global__ __launch_bounds__(128) void prop_kernel(const int* __restrict__ offsets,
                                                   const int* __restrict__ row_sorted,
                                                   const float* __restrict__ ew_sorted,
                                                   const float* __restrict__ in,
                                                   float* __restrict__ out) {
    int c = blockIdx.x;
    int ch = threadIdx.x;
    int s = offsets[c], e = offsets[c + 1];
    float acc = 0.0f;
    for (int i = s; i < e; i++) {
        int r = row_sorted[i];
        float w = ew_sorted[i];
        acc += w * in[(size_t)r * HD + ch];
    }
    out[(size_t)c * HD + ch] = acc;
}

// ---------------- Generic GEMM: out[N,128] = cat(srcs)[N,NT*128] @ W + bias (+res)(/den) ----------------
#define GR 16
template <int NT>
__global__ __launch_bounds__(128) void gemm128(
    const float* __restrict__ s0, const float* __restrict__ s1, const float* __restrict__ s2,
    const float* __restrict__ s3, const float* __restrict__ s4,
    const float* __restrict__ W, const float* __restrict__ bias,
    const float* __restrict__ res, const float* __restrict__ den,
    float* __restrict__ out, int N) {
    __shared__ float At[GR][HD];
    const float* srcs[5] = {s0, s1, s2, s3, s4};
    int j = threadIdx.x;
    int row0 = blockIdx.x * GR;
    float acc[GR];
    #pragma unroll
    for (int r = 0; r < GR; r++) acc[r] = 0.0f;
    for (int t = 0; t < NT; t++) {
        const float* A = srcs[t];
        __syncthreads();
        #pragma unroll
        for (int r = 0; r < GR; r++) {
            int n = row0 + r;
            At[r][j] = (n < N) ? A[(size_t)n * HD + j] : 0.0f;
        }
        __syncthreads();
        const float* Wt = W + (size_t)t * HD * HD;
        for (int kk = 0; kk < HD; kk += 4) {
            float4 w4;
            w4.x = Wt[(kk + 0) * HD + j];
            w4.y = Wt[(kk + 1) * HD + j];
            w4.z = Wt[(kk + 2) * HD + j];
            w4.w = Wt[(kk + 3) * HD + j];
            #pragma unroll
            for (int r = 0; r < GR; r++) {
                float4 a = *(const float4*)&At[r][kk];
                acc[r] += a.x * w4.x + a.y * w4.y + a.z * w4.z + a.w * w4.w;
            }
        }
    }
    float b = bias ? bias[j] : 0.0f;
    #pragma unroll
    for (int r = 0; r < GR; r++) {
        int n = row0 + r;
        if (n >= N) continue;
        float v = acc[r] + b;
        if (res) v += res[(size_t)n * HD + j];
        if (den) v /= den[n];
        out[(size_t)n * HD + j] = v;
    }
}

// ---------------- BatchNorm ----------------
__global__ __launch_bounds__(256) void bn_stats(const float* __restrict__ z,
                                                float* __restrict__ sums,
                                                float* __restrict__ sumsq, int N) {
    int ch = threadIdx.x & 127;
    int rw = threadIdx.x >> 7;
    float s = 0.0f, ss = 0.0f;
    for (int n = blockIdx.x * 2 + rw; n < N; n += gridDim.x * 2) {
        float v = z[(size_t)n * HD + ch];
        s += v;
        ss += v * v;
    }
    __shared__ float Ls[256], Lss[256];
    Ls[threadIdx.x] = s;
    Lss[threadIdx.x] = ss;
    __syncthreads();
    if (rw == 0) {
        atomicAdd(&sums[ch], s + Ls[threadIdx.x + 128]);
        atomicAdd(&sumsq[ch], ss + Lss[threadIdx.x + 128]);
    }
}

__global__ void bn_finalize(const float* __restrict__ sums, const float* __restrict__ sumsq,
                            const float* __restrict__ g, const float* __restrict__ b,
                            float* __restrict__ scale, float* __restrict__ shift, int N) {
    int ch = threadIdx.x;
    float m = sums[ch] / (float)N;
    float var = sumsq[ch] / (float)N - m * m;
    float sc = g[ch] * rsqrtf(var + EPS_BN);
    scale[ch] = sc;
    shift[ch] = b[ch] - m * sc;
}

__global__ void bn_apply(const float4* __restrict__ z, float4* __restrict__ h,
                         const float* __restrict__ scale, const float* __restrict__ shift,
                         int n4) {
    int i = blockIdx.x * blockDim.x + threadIdx.x;
    if (i >= n4) return;
    int c4 = i & 31;
    float4 zv = z[i];
    float4 sc = ((const float4*)scale)[c4];
    float4 sh = ((const float4*)shift)[c4];
    float4 hv;
    hv.x = fmaxf(zv.x * sc.x + sh.x, 0.0f);
    hv.y = fmaxf(zv.y * sc.y + sh.y, 0.0f);
    hv.z = fmaxf(zv.z * sc.z + sh.z, 0.0f);
    hv.w = fmaxf(zv.w * sc.w + sh.w, 0.0f);
    h[i] = hv;
}

// ---------------- Attention helpers ----------------
__global__ __launch_bounds__(256) void rownorm(float* __restrict__ q, int N) {
    int lane = threadIdx.x & 63;
    int wv = threadIdx.x >> 6;
    int n = blockIdx.x * 4 + wv;
    if (n >= N) return;
    float2 v = *(const float2*)(q + (size_t)n * HD + lane * 2);
    float s = v.x * v.x + v.y * v.y;
    #pragma unroll
    for (int o = 32; o > 0; o >>= 1) s += __shfl_down(s, o, 64);
    s = __shfl(s, 0, 64);
    float inv = rsqrtf(s);
    v.x *= inv;
    v.y *= inv;
    *(float2*)(q + (size_t)n * HD + lane * 2) = v;
}

// kvs[m][d] = sum_n kn[n][m]*v[n][d]; ksum[m]=sum kn; vsum[d]=sum v
__global__ __launch_bounds__(256) void kvs_kernel(const float* __restrict__ kn,
                                                  const float* __restrict__ v,
                                                  float* __restrict__ kvs,
                                                  float* __restrict__ ksum,
                                                  float* __restrict__ vsum, int N) {
    __shared__ float Lk[64][HD];
    __shared__ float Lv[64][HD];
    int t = threadIdx.x;
    int d = t & 127;
    int mg = t >> 7;  // 0 or 1: m-half
    float acc[64];
    #pragma unroll
    for (int mi = 0; mi < 64; mi++) acc[mi] = 0.0f;
    float sum_p = 0.0f;
    for (int base = blockIdx.x * 64; base < N; base += gridDim.x * 64) {
        for (int i = t; i < 64 * HD; i += 256) {
            int r = i >> 7, d2 = i & 127;
            int rowi = base + r;
            float kv = 0.0f, vv = 0.0f;
            if (rowi < N) {
                kv = kn[(size_t)rowi * HD + d2];
                vv = v[(size_t)rowi * HD + d2];
            }
            Lk[r][d2] = kv;
            Lv[r][d2] = vv;
        }
        __syncthreads();
        for (int r = 0; r < 64; r++) {
            float vv = Lv[r][d];
            sum_p += (mg == 0) ? Lk[r][d] : vv;
            #pragma unroll
            for (int mi = 0; mi < 64; mi++) acc[mi] += Lk[r][(mg << 6) + mi] * vv;
        }
        __syncthreads();
    }
    #pragma unroll
    for (int mi = 0; mi < 64; mi++) atomicAdd(&kvs[((mg << 6) + mi) * HD + d], acc[mi]);
    if (mg == 0)
        atomicAdd(&ksum[d], sum_p);
    else
        atomicAdd(&vsum[d], sum_p);
}

__global__ __launch_bounds__(256) void den_kernel(const float* __restrict__ qn,
                                                  const float* __restrict__ ksum,
                                                  float* __restrict__ den, int N) {
    int lane = threadIdx.x & 63;
    int wv = threadIdx.x >> 6;
    int n = blockIdx.x * 4 + wv;
    if (n >= N) return;
    float2 qv = *(const float2*)(qn + (size_t)n * HD + lane * 2);
    float2 kv = *(const float2*)(ksum + lane * 2);
    float s = qv.x * kv.x + qv.y * kv.y;
    #pragma unroll
    for (int o = 32; o > 0; o >>= 1) s += __shfl_down(s, o, 64);
    if (lane == 0) den[n] = s + (float)NN;
}

// ---------------- Output GEMM [N,128]@[128,40] ----------------
__global__ void out_gemm(const float* __restrict__ h, const float* __restrict__ W,
                         const float* __restrict__ b, float* __restrict__ out, int N) {
    int idx = blockIdx.x * blockDim.x + threadIdx.x;
    if (idx >= N * 40) return;
    int n = idx / 40;
    int j = idx - n * 40;
    float acc = b[j];
    const float* hr = h + (size_t)n * HD;
    for (int k = 0; k < HD; k++) acc += hr[k] * W[k * 40 + j];
    out[idx] = acc;
}

extern "C" void kernel_launch(void* const* d_in, const int* in_sizes, int n_in,
                              void* d_out, int out_size, void* d_ws, size_t ws_size,
                              hipStream_t stream) {
    const float* x = (const float*)d_in[0];
    const int* eidx = (const int*)d_in[1];
    const float* W_in = (const float*)d_in[2];
    const float* b_in = (const float*)d_in[3];
    const float* Wq = (const float*)d_in[4];
    const float* bq = (const float*)d_in[5];
    const float* Wk = (const float*)d_in[6];
    const float* bk = (const float*)d_in[7];
    const float* Wfc = (const float*)d_in[8];
    const float* bfc = (const float*)d_in[9];
    const float* W_out = (const float*)d_in[10];
    const float* b_out = (const float*)d_in[11];
    const float* bn_g = (const float*)d_in[12];
    const float* bn_b = (const float*)d_in[13];
    float* out = (float*)d_out;

    const int N = NN, E = NE;
    const int* rowp = eidx;
    const int* colp = eidx + E;

    char* ws = (char*)d_ws;
    size_t off = 0;
    auto nxt = [&](size_t bytes) -> void* {
        void* p = ws + off;
        off += (bytes + 255) & ~(size_t)255;
        return p;
    };
    int* counts = (int*)nxt((size_t)N * 4);
    int* offsets = (int*)nxt((size_t)(N + 1) * 4);
    int* cursor = (int*)nxt((size_t)N * 4);
    int* row_sorted = (int*)nxt((size_t)E * 4);
    float* ew_sorted = (float*)nxt((size_t)E * 4);
    float* dis = (float*)nxt((size_t)N * 4);
    float* den = (float*)nxt((size_t)N * 4);
    float* kvs = (float*)nxt((size_t)HD * HD * 4);  // + ksum + vsum contiguous
    float* ksum = (float*)nxt((size_t)HD * 4);
    float* vsum = (float*)nxt((size_t)HD * 4);
    float* bnsum = (float*)nxt((size_t)HD * 4);  // + bnsumsq contiguous
    float* bnsumsq = (float*)nxt((size_t)HD * 4);
    float* bnscale = (float*)nxt((size_t)HD * 4);
    float* bnshift = (float*)nxt((size_t)HD * 4);
    float* h = (float*)nxt((size_t)N * HD * 4);
    float* hn = (float*)nxt((size_t)N * HD * 4);
    float* qb = (float*)nxt((size_t)N * HD * 4);
    float* kb = (float*)nxt((size_t)N * HD * 4);
    float* p1 = (float*)nxt((size_t)N * HD * 4);
    float* p2 = (float*)nxt((size_t)N * HD * 4);
    float* p3 = (float*)nxt((size_t)N * HD * 4);

    // ---- CSR build ----
    hipMemsetAsync(counts, 0, (size_t)N * 4, stream);
    count_edges<<<(E + 255) / 256, 256, 0, stream>>>(colp, counts, E);
    dis_kernel<<<(N + 255) / 256, 256, 0, stream>>>(counts, dis, N);
    scan_kernel<<<1, 1024, 0, stream>>>(counts, offsets, N);
    hipMemsetAsync(cursor, 0, (size_t)N * 4, stream);
    scatter_edges<<<(E + 255) / 256, 256, 0, stream>>>(rowp, colp, dis, offsets, cursor,
                                                       row_sorted, ew_sorted, E);

    // ---- input layer: h = relu(bn(x @ W_in + b_in)) ----
    gemm128<1><<<(N + GR - 1) / GR, 128, 0, stream>>>(x, nullptr, nullptr, nullptr, nullptr,
                                                      W_in, b_in, nullptr, nullptr, hn, N);
    hipMemsetAsync(bnsum, 0, 1024, stream);
    bn_stats<<<400, 256, 0, stream>>>(hn, bnsum, bnsumsq, N);
    bn_finalize<<<1, 128, 0, stream>>>(bnsum, bnsumsq, bn_g, bn_b, bnscale, bnshift, N);
    bn_apply<<<(N * 32 + 255) / 256, 256, 0, stream>>>((const float4*)hn, (float4*)h, bnscale,
                                                       bnshift, N * 32);

    for (int i = 0; i < 2; i++) {
        const float* Wq_i = Wq + (size_t)i * HD * HD;
        const float* bq_i = bq + (size_t)i * HD;
        const float* Wk_i = Wk + (size_t)i * HD * HD;
        const float* bk_i = bk + (size_t)i * HD;
        const float* Wfc_i = Wfc + (size_t)i * 640 * HD;
        const float* bfc_i = bfc + (size_t)i * HD;

        // K-hop diffusion
        prop_kernel<<<N, 128, 0, stream>>>(offsets, row_sorted, ew_sorted, h, p1);
        prop_kernel<<<N, 128, 0, stream>>>(offsets, row_sorted, ew_sorted, p1, p2);
        prop_kernel<<<N, 128, 0, stream>>>(offsets, row_sorted, ew_sorted, p2, p3);

        // attention
        gemm128<1><<<(N + GR - 1) / GR, 128, 0, stream>>>(h, nullptr, nullptr, nullptr, nullptr,
                                                          Wq_i, bq_i, nullptr, nullptr, qb, N);
        gemm128<1><<<(N + GR - 1) / GR, 128, 0, stream>>>(h, nullptr, nullptr, nullptr, nullptr,
                                                          Wk_i, bk_i, nullptr, nullptr, kb, N);
        rownorm<<<(N + 3) / 4, 256, 0, stream>>>(qb, N);
        rownorm<<<(N + 3) / 4, 256, 0, stream>>>(kb, N);
        hipMemsetAsync(kvs, 0, (size_t)(HD * HD + 2 * HD) * 4 + 512, stream);
        kvs_kernel<<<256, 256, 0, stream>>>(kb, h, kvs, ksum, vsum, N);
        den_kernel<<<(N + 3) / 4, 256, 0, stream>>>(qb, ksum, den, N);
        // x1 = (qn @ kvs + vsum)/den, overwrite qb
        gemm128<1><<<(N + GR - 1) / GR, 128, 0, stream>>>(qb, nullptr, nullptr, nullptr, nullptr,
                                                          kvs, vsum, nullptr, den, qb, N);

        // z = cat(x1,h,p1,p2,p3) @ Wfc + bfc + h
        gemm128<5><<<(N + GR - 1) / GR, 128, 0, stream>>>(qb, h, p1, p2, p3, Wfc_i, bfc_i, h,
                                                          nullptr, hn, N);
        hipMemsetAsync(bnsum, 0, 1024, stream);
        bn_stats<<<400, 256, 0, stream>>>(hn, bnsum, bnsumsq, N);
        bn_finalize<<<1, 128, 0, stream>>>(bnsum, bnsumsq, bn_g + (size_t)(i + 1) * HD,
                                           bn_b + (size_t)(i + 1) * HD, bnscale, bnshift, N);
        bn_apply<<<(N * 32 + 255) / 256, 256, 0, stream>>>((const float4*)hn, (float4*)h, bnscale,
                                                           bnshift, N * 32);
    }

    out_gemm<<<(N * 40 + 255) / 256, 256, 0, stream>>>(h, W_out, b_out, out, N);
}

// Round 2
// 1665.231 us; speedup vs baseline: 1.2248x; 1.2248x over previous
//
#include <hip/hip_runtime.h>
#include <hip/hip_bf16.h>
#include <math.h>

#define NN 50000
#define NE 800000
#define HD 128
#define EPS_BN 1e-5f

typedef __bf16 bf16_t;
typedef bf16_t bf16x8 __attribute__((ext_vector_type(8)));
typedef float f32x4 __attribute__((ext_vector_type(4)));

// ---------------- CSR build ----------------
__global__ void count_edges(const int* __restrict__ col, int* __restrict__ counts, int E) {
    int e = blockIdx.x * 256 + threadIdx.x;
    if (e >= E) return;
    atomicAdd(&counts[col[e]], 1);
}

__global__ void dis_kernel(const int* __restrict__ counts, float* __restrict__ dis, int N) {
    int i = blockIdx.x * 256 + threadIdx.x;
    if (i >= N) return;
    int c = counts[i];
    dis[i] = (c > 0) ? rsqrtf((float)c) : 0.0f;
}

__global__ __launch_bounds__(1024) void scan_kernel(const int* __restrict__ counts,
                                                    int* __restrict__ offsets, int n) {
    __shared__ int wsum[16];
    int tid = threadIdx.x;
    int lane = tid & 63;
    int w = tid >> 6;
    int carry = 0;
    for (int base = 0; base < n; base += 1024) {
        int i = base + tid;
        int v = (i < n) ? counts[i] : 0;
        int x = v;
        #pragma unroll
        for (int o = 1; o < 64; o <<= 1) {
            int t = __shfl_up(x, o, 64);
            if (lane >= o) x += t;
        }
        if (lane == 63) wsum[w] = x;
        __syncthreads();
        if (w == 0 && lane < 16) {
            int y = wsum[lane];
            #pragma unroll
            for (int o = 1; o < 16; o <<= 1) {
                int t = __shfl_up(y, o, 64);
                if (lane >= o) y += t;
            }
            wsum[lane] = y;
        }
        __syncthreads();
        int wpre = (w > 0) ? wsum[w - 1] : 0;
        int incl = carry + wpre + x;
        if (i < n) offsets[i] = incl - v;  // exclusive
        carry += wsum[15];
        __syncthreads();
    }
    if (tid == 0) offsets[n] = carry;
}

__global__ void scatter_edges(const int* __restrict__ row, const int* __restrict__ col,
                              const float* __restrict__ dis, const int* __restrict__ offsets,
                              int* __restrict__ cursor, int* __restrict__ row_sorted,
                              float* __restrict__ ew_sorted, int E) {
    int e = blockIdx.x * 256 + threadIdx.x;
    if (e >= E) return;
    int c = col[e], r = row[e];
    int pos = offsets[c] + atomicAdd(&cursor[c], 1);
    row_sorted[pos] = r;
    ew_sorted[pos] = dis[c] * dis[r];
}

// ---------------- Graph propagation (CSR gather) ----------------
__global__ __launch_bounds__(128) void prop_kernel(const int* __restrict__ offsets,
                                                   const int* __restrict__ row_sorted,
                                                   const float* __restrict__ ew_sorted,
                                                   const float* __restrict__ in,
                                                   float* __restrict__ out) {
    int c = blockIdx.x;
    int ch = threadIdx.x;
    int s = offsets[c], e = offsets[c + 1];
    float acc = 0.0f;
    for (int i = s; i < e; i++) {
        int r = row_sorted[i];
        float w = ew_sorted[i];
        acc += w * in[(size_t)r * HD + ch];
    }
    out[(size_t)c * HD + ch] = acc;
}

// ---------------- Weight transpose + bf16 convert: dst[n][k] = src[k][n] ----------------
__global__ void wcvt(const float* __restrict__ src, bf16_t* __restrict__ dst, int Ktot) {
    int i = blockIdx.x * 256 + threadIdx.x;
    if (i >= Ktot * 128) return;
    int k = i >> 7;
    int n = i & 127;
    dst[(size_t)n * Ktot + k] = (bf16_t)src[i];
}

// ---------------- MFMA GEMM: out[N,128] = cat(srcs)[N,NT*128] @ W + bias (+res)(/den) ----------------
// Wt is pre-transposed bf16: Wt[n][k], n in [0,128), k in [0,NT*128)
template <int NT>
__global__ __launch_bounds__(256) void gemm_mfma(
    const float* __restrict__ s0, const float* __restrict__ s1, const float* __restrict__ s2,
    const float* __restrict__ s3, const float* __restrict__ s4,
    const bf16_t* __restrict__ Wt, const float* __restrict__ bias,
    const float* __restrict__ res, const float* __restrict__ den,
    float* __restrict__ out, int N) {
    const int Ktot = NT * HD;
    const float* srcs[5] = {s0, s1, s2, s3, s4};
    int wave = threadIdx.x >> 6;
    int lane = threadIdx.x & 63;
    int quad = lane >> 4;
    int l16 = lane & 15;
    int m0 = blockIdx.x * 64 + wave * 16;
    int arow = m0 + l16;  // row this lane loads for the A fragment

    f32x4 acc[8] = {};

    for (int kc = 0; kc < Ktot; kc += 32) {
        int s = kc >> 7;
        int klocal = kc & 127;
        // A fragment: A[m = lane&15][k = quad*8 + j]
        bf16x8 afrag = {};
        if (arow < N) {
            const float* ap = srcs[s] + ((size_t)arow << 7) + klocal + quad * 8;
            float4 a0 = *(const float4*)ap;
            float4 a1 = *(const float4*)(ap + 4);
            afrag[0] = (bf16_t)a0.x; afrag[1] = (bf16_t)a0.y;
            afrag[2] = (bf16_t)a0.z; afrag[3] = (bf16_t)a0.w;
            afrag[4] = (bf16_t)a1.x; afrag[5] = (bf16_t)a1.y;
            afrag[6] = (bf16_t)a1.z; afrag[7] = (bf16_t)a1.w;
        }
        #pragma unroll
        for (int t = 0; t < 8; t++) {
            // B fragment: B[k = quad*8 + j][n = 16t + lane&15] from Wt[n][k]
            const bf16_t* bp = Wt + (size_t)(t * 16 + l16) * Ktot + kc + quad * 8;
            bf16x8 bfrag = *(const bf16x8*)bp;
            acc[t] = __builtin_amdgcn_mfma_f32_16x16x32_bf16(afrag, bfrag, acc[t], 0, 0, 0);
        }
    }
    // epilogue: C/D layout col = lane&15 (+16t), row = quad*4 + reg
    #pragma unroll
    for (int t = 0; t < 8; t++) {
        int c = t * 16 + l16;
        float b = bias ? bias[c] : 0.0f;
        #pragma unroll
        for (int r = 0; r < 4; r++) {
            int rr = m0 + quad * 4 + r;
            if (rr < N) {
                float v = acc[t][r] + b;
                if (res) v += res[((size_t)rr << 7) + c];
                if (den) v /= den[rr];
                out[((size_t)rr << 7) + c] = v;
            }
        }
    }
}

// ---------------- BatchNorm ----------------
__global__ __launch_bounds__(256) void bn_stats(const float* __restrict__ z,
                                                float* __restrict__ sums,
                                                float* __restrict__ sumsq, int N) {
    int ch = threadIdx.x & 127;
    int rw = threadIdx.x >> 7;
    float s = 0.0f, ss = 0.0f;
    for (int n = blockIdx.x * 2 + rw; n < N; n += gridDim.x * 2) {
        float v = z[(size_t)n * HD + ch];
        s += v;
        ss += v * v;
    }
    __shared__ float Ls[256], Lss[256];
    Ls[threadIdx.x] = s;
    Lss[threadIdx.x] = ss;
    __syncthreads();
    if (rw == 0) {
        atomicAdd(&sums[ch], s + Ls[threadIdx.x + 128]);
        atomicAdd(&sumsq[ch], ss + Lss[threadIdx.x + 128]);
    }
}

__global__ void bn_finalize(const float* __restrict__ sums, const float* __restrict__ sumsq,
                            const float* __restrict__ g, const float* __restrict__ b,
                            float* __restrict__ scale, float* __restrict__ shift, int N) {
    int ch = threadIdx.x;
    float m = sums[ch] / (float)N;
    float var = sumsq[ch] / (float)N - m * m;
    float sc = g[ch] * rsqrtf(var + EPS_BN);
    scale[ch] = sc;
    shift[ch] = b[ch] - m * sc;
}

__global__ void bn_apply(const float4* __restrict__ z, float4* __restrict__ h,
                         const float* __restrict__ scale, const float* __restrict__ shift,
                         int n4) {
    int i = blockIdx.x * blockDim.x + threadIdx.x;
    if (i >= n4) return;
    int c4 = i & 31;
    float4 zv = z[i];
    float4 sc = ((const float4*)scale)[c4];
    float4 sh = ((const float4*)shift)[c4];
    float4 hv;
    hv.x = fmaxf(zv.x * sc.x + sh.x, 0.0f);
    hv.y = fmaxf(zv.y * sc.y + sh.y, 0.0f);
    hv.z = fmaxf(zv.z * sc.z + sh.z, 0.0f);
    hv.w = fmaxf(zv.w * sc.w + sh.w, 0.0f);
    h[i] = hv;
}

// ---------------- Attention helpers ----------------
__global__ __launch_bounds__(256) void rownorm(float* __restrict__ q, int N) {
    int lane = threadIdx.x & 63;
    int wv = threadIdx.x >> 6;
    int n = blockIdx.x * 4 + wv;
    if (n >= N) return;
    float2 v = *(const float2*)(q + (size_t)n * HD + lane * 2);
    float s = v.x * v.x + v.y * v.y;
    #pragma unroll
    for (int o = 32; o > 0; o >>= 1) s += __shfl_down(s, o, 64);
    s = __shfl(s, 0, 64);
    float inv = rsqrtf(s);
    v.x *= inv;
    v.y *= inv;
    *(float2*)(q + (size_t)n * HD + lane * 2) = v;
}

// kvs[m][d] = sum_n kn[n][m]*v[n][d]; ksum[m]=sum kn; vsum[d]=sum v
__global__ __launch_bounds__(256) void kvs_kernel(const float* __restrict__ kn,
                                                  const float* __restrict__ v,
                                                  float* __restrict__ kvs,
                                                  float* __restrict__ ksum,
                                                  float* __restrict__ vsum, int N) {
    __shared__ float Lk[64][HD];
    __shared__ float Lv[64][HD];
    int t = threadIdx.x;
    int d = t & 127;
    int mg = t >> 7;  // 0 or 1: m-half
    float acc[64];
    #pragma unroll
    for (int mi = 0; mi < 64; mi++) acc[mi] = 0.0f;
    float sum_p = 0.0f;
    for (int base = blockIdx.x * 64; base < N; base += gridDim.x * 64) {
        for (int i = t; i < 64 * HD; i += 256) {
            int r = i >> 7, d2 = i & 127;
            int rowi = base + r;
            float kv = 0.0f, vv = 0.0f;
            if (rowi < N) {
                kv = kn[(size_t)rowi * HD + d2];
                vv = v[(size_t)rowi * HD + d2];
            }
            Lk[r][d2] = kv;
            Lv[r][d2] = vv;
        }
        __syncthreads();
        for (int r = 0; r < 64; r++) {
            float vv = Lv[r][d];
            sum_p += (mg == 0) ? Lk[r][d] : vv;
            #pragma unroll
            for (int mi = 0; mi < 64; mi++) acc[mi] += Lk[r][(mg << 6) + mi] * vv;
        }
        __syncthreads();
    }
    #pragma unroll
    for (int mi = 0; mi < 64; mi++) atomicAdd(&kvs[((mg << 6) + mi) * HD + d], acc[mi]);
    if (mg == 0)
        atomicAdd(&ksum[d], sum_p);
    else
        atomicAdd(&vsum[d], sum_p);
}

__global__ __launch_bounds__(256) void den_kernel(const float* __restrict__ qn,
                                                  const float* __restrict__ ksum,
                                                  float* __restrict__ den, int N) {
    int lane = threadIdx.x & 63;
    int wv = threadIdx.x >> 6;
    int n = blockIdx.x * 4 + wv;
    if (n >= N) return;
    float2 qv = *(const float2*)(qn + (size_t)n * HD + lane * 2);
    float2 kv = *(const float2*)(ksum + lane * 2);
    float s = qv.x * kv.x + qv.y * kv.y;
    #pragma unroll
    for (int o = 32; o > 0; o >>= 1) s += __shfl_down(s, o, 64);
    if (lane == 0) den[n] = s + (float)NN;
}

// ---------------- Output GEMM [N,128]@[128,40] ----------------
__global__ void out_gemm(const float* __restrict__ h, const float* __restrict__ W,
                         const float* __restrict__ b, float* __restrict__ out, int N) {
    int idx = blockIdx.x * blockDim.x + threadIdx.x;
    if (idx >= N * 40) return;
    int n = idx / 40;
    int j = idx - n * 40;
    float acc = b[j];
    const float* hr = h + (size_t)n * HD;
    for (int k = 0; k < HD; k++) acc += hr[k] * W[k * 40 + j];
    out[idx] = acc;
}

extern "C" void kernel_launch(void* const* d_in, const int* in_sizes, int n_in,
                              void* d_out, int out_size, void* d_ws, size_t ws_size,
                              hipStream_t stream) {
    const float* x = (const float*)d_in[0];
    const int* eidx = (const int*)d_in[1];
    const float* W_in = (const float*)d_in[2];
    const float* b_in = (const float*)d_in[3];
    const float* Wq = (const float*)d_in[4];
    const float* bq = (const float*)d_in[5];
    const float* Wk = (const float*)d_in[6];
    const float* bk = (const float*)d_in[7];
    const float* Wfc = (const float*)d_in[8];
    const float* bfc = (const float*)d_in[9];
    const float* W_out = (const float*)d_in[10];
    const float* b_out = (const float*)d_in[11];
    const float* bn_g = (const float*)d_in[12];
    const float* bn_b = (const float*)d_in[13];
    float* out = (float*)d_out;

    const int N = NN, E = NE;
    const int* rowp = eidx;
    const int* colp = eidx + E;

    char* ws = (char*)d_ws;
    size_t off = 0;
    auto nxt = [&](size_t bytes) -> void* {
        void* p = ws + off;
        off += (bytes + 255) & ~(size_t)255;
        return p;
    };
    int* counts = (int*)nxt((size_t)N * 4);
    int* offsets = (int*)nxt((size_t)(N + 1) * 4);
    int* cursor = (int*)nxt((size_t)N * 4);
    int* row_sorted = (int*)nxt((size_t)E * 4);
    float* ew_sorted = (float*)nxt((size_t)E * 4);
    float* dis = (float*)nxt((size_t)N * 4);
    float* den = (float*)nxt((size_t)N * 4);
    float* kvs = (float*)nxt((size_t)HD * HD * 4);  // + ksum + vsum contiguous
    float* ksum = (float*)nxt((size_t)HD * 4);
    float* vsum = (float*)nxt((size_t)HD * 4);
    float* bnsum = (float*)nxt((size_t)HD * 4);  // + bnsumsq contiguous
    float* bnsumsq = (float*)nxt((size_t)HD * 4);
    float* bnscale = (float*)nxt((size_t)HD * 4);
    float* bnshift = (float*)nxt((size_t)HD * 4);
    float* h = (float*)nxt((size_t)N * HD * 4);
    float* hn = (float*)nxt((size_t)N * HD * 4);
    float* qb = (float*)nxt((size_t)N * HD * 4);
    float* kb = (float*)nxt((size_t)N * HD * 4);
    float* p1 = (float*)nxt((size_t)N * HD * 4);
    float* p2 = (float*)nxt((size_t)N * HD * 4);
    float* p3 = (float*)nxt((size_t)N * HD * 4);
    // bf16 transposed weights
    bf16_t* Wt_in = (bf16_t*)nxt((size_t)HD * HD * 2);
    bf16_t* Wt_q = (bf16_t*)nxt((size_t)2 * HD * HD * 2);
    bf16_t* Wt_k = (bf16_t*)nxt((size_t)2 * HD * HD * 2);
    bf16_t* Wt_fc = (bf16_t*)nxt((size_t)2 * 640 * HD * 2);
    bf16_t* kvsT = (bf16_t*)nxt((size_t)HD * HD * 2);

    const int GB = (N + 63) / 64;  // gemm_mfma grid

    // ---- CSR build ----
    hipMemsetAsync(counts, 0, (size_t)N * 4, stream);
    count_edges<<<(E + 255) / 256, 256, 0, stream>>>(colp, counts, E);
    dis_kernel<<<(N + 255) / 256, 256, 0, stream>>>(counts, dis, N);
    scan_kernel<<<1, 1024, 0, stream>>>(counts, offsets, N);
    hipMemsetAsync(cursor, 0, (size_t)N * 4, stream);
    scatter_edges<<<(E + 255) / 256, 256, 0, stream>>>(rowp, colp, dis, offsets, cursor,
                                                       row_sorted, ew_sorted, E);

    // ---- weight transposes ----
    wcvt<<<64, 256, 0, stream>>>(W_in, Wt_in, HD);
    wcvt<<<64, 256, 0, stream>>>(Wq, Wt_q, HD);
    wcvt<<<64, 256, 0, stream>>>(Wq + HD * HD, Wt_q + HD * HD, HD);
    wcvt<<<64, 256, 0, stream>>>(Wk, Wt_k, HD);
    wcvt<<<64, 256, 0, stream>>>(Wk + HD * HD, Wt_k + HD * HD, HD);
    wcvt<<<320, 256, 0, stream>>>(Wfc, Wt_fc, 640);
    wcvt<<<320, 256, 0, stream>>>(Wfc + 640 * HD, Wt_fc + 640 * HD, 640);

    // ---- input layer: h = relu(bn(x @ W_in + b_in)) ----
    gemm_mfma<1><<<GB, 256, 0, stream>>>(x, nullptr, nullptr, nullptr, nullptr, Wt_in, b_in,
                                         nullptr, nullptr, hn, N);
    hipMemsetAsync(bnsum, 0, 1024, stream);
    bn_stats<<<400, 256, 0, stream>>>(hn, bnsum, bnsumsq, N);
    bn_finalize<<<1, 128, 0, stream>>>(bnsum, bnsumsq, bn_g, bn_b, bnscale, bnshift, N);
    bn_apply<<<(N * 32 + 255) / 256, 256, 0, stream>>>((const float4*)hn, (float4*)h, bnscale,
                                                       bnshift, N * 32);

    for (int i = 0; i < 2; i++) {
        const float* bq_i = bq + (size_t)i * HD;
        const float* bk_i = bk + (size_t)i * HD;
        const float* bfc_i = bfc + (size_t)i * HD;
        bf16_t* Wt_q_i = Wt_q + (size_t)i * HD * HD;
        bf16_t* Wt_k_i = Wt_k + (size_t)i * HD * HD;
        bf16_t* Wt_fc_i = Wt_fc + (size_t)i * 640 * HD;

        // K-hop diffusion
        prop_kernel<<<N, 128, 0, stream>>>(offsets, row_sorted, ew_sorted, h, p1);
        prop_kernel<<<N, 128, 0, stream>>>(offsets, row_sorted, ew_sorted, p1, p2);
        prop_kernel<<<N, 128, 0, stream>>>(offsets, row_sorted, ew_sorted, p2, p3);

        // attention
        gemm_mfma<1><<<GB, 256, 0, stream>>>(h, nullptr, nullptr, nullptr, nullptr, Wt_q_i, bq_i,
                                             nullptr, nullptr, qb, N);
        gemm_mfma<1><<<GB, 256, 0, stream>>>(h, nullptr, nullptr, nullptr, nullptr, Wt_k_i, bk_i,
                                             nullptr, nullptr, kb, N);
        rownorm<<<(N + 3) / 4, 256, 0, stream>>>(qb, N);
        rownorm<<<(N + 3) / 4, 256, 0, stream>>>(kb, N);
        hipMemsetAsync(kvs, 0, (size_t)(HD * HD + 2 * HD) * 4 + 512, stream);
        kvs_kernel<<<256, 256, 0, stream>>>(kb, h, kvs, ksum, vsum, N);
        den_kernel<<<(N + 3) / 4, 256, 0, stream>>>(qb, ksum, den, N);
        wcvt<<<64, 256, 0, stream>>>(kvs, kvsT, HD);
        // x1 = (qn @ kvs + vsum)/den, overwrite qb
        gemm_mfma<1><<<GB, 256, 0, stream>>>(qb, nullptr, nullptr, nullptr, nullptr, kvsT, vsum,
                                             nullptr, den, qb, N);

        // z = cat(x1,h,p1,p2,p3) @ Wfc + bfc + h
        gemm_mfma<5><<<GB, 256, 0, stream>>>(qb, h, p1, p2, p3, Wt_fc_i, bfc_i, h, nullptr, hn,
                                             N);
        hipMemsetAsync(bnsum, 0, 1024, stream);
        bn_stats<<<400, 256, 0, stream>>>(hn, bnsum, bnsumsq, N);
        bn_finalize<<<1, 128, 0, stream>>>(bnsum, bnsumsq, bn_g + (size_t)(i + 1) * HD,
                                           bn_b + (size_t)(i + 1) * HD, bnscale, bnshift, N);
        bn_apply<<<(N * 32 + 255) / 256, 256, 0, stream>>>((const float4*)hn, (float4*)h, bnscale,
                                                           bnshift, N * 32);
    }

    out_gemm<<<(N * 40 + 255) / 256, 256, 0, stream>>>(h, W_out, b_out, out, N);
}

// Round 3
// 1194.227 us; speedup vs baseline: 1.7079x; 1.3944x over previous
//
#include <hip/hip_runtime.h>
#include <hip/hip_bf16.h>
#include <math.h>

#define NN 50000
#define NE 800000
#define HD 128
#define EPS_BN 1e-5f

typedef __bf16 bf16_t;
typedef bf16_t bf16x8 __attribute__((ext_vector_type(8)));
typedef bf16_t bf16x4 __attribute__((ext_vector_type(4)));
typedef float f32x4 __attribute__((ext_vector_type(4)));

// ---------------- CSR build ----------------
__global__ void count_edges(const int* __restrict__ col, int* __restrict__ counts, int E) {
    int e = blockIdx.x * 256 + threadIdx.x;
    if (e >= E) return;
    atomicAdd(&counts[col[e]], 1);
}

__global__ void dis_kernel(const int* __restrict__ counts, float* __restrict__ dis, int N) {
    int i = blockIdx.x * 256 + threadIdx.x;
    if (i >= N) return;
    int c = counts[i];
    dis[i] = (c > 0) ? rsqrtf((float)c) : 0.0f;
}

__global__ __launch_bounds__(1024) void scan_kernel(const int* __restrict__ counts,
                                                    int* __restrict__ offsets, int n) {
    __shared__ int wsum[16];
    int tid = threadIdx.x;
    int lane = tid & 63;
    int w = tid >> 6;
    int carry = 0;
    for (int base = 0; base < n; base += 1024) {
        int i = base + tid;
        int v = (i < n) ? counts[i] : 0;
        int x = v;
        #pragma unroll
        for (int o = 1; o < 64; o <<= 1) {
            int t = __shfl_up(x, o, 64);
            if (lane >= o) x += t;
        }
        if (lane == 63) wsum[w] = x;
        __syncthreads();
        if (w == 0 && lane < 16) {
            int y = wsum[lane];
            #pragma unroll
            for (int o = 1; o < 16; o <<= 1) {
                int t = __shfl_up(y, o, 64);
                if (lane >= o) y += t;
            }
            wsum[lane] = y;
        }
        __syncthreads();
        int wpre = (w > 0) ? wsum[w - 1] : 0;
        int incl = carry + wpre + x;
        if (i < n) offsets[i] = incl - v;  // exclusive
        carry += wsum[15];
        __syncthreads();
    }
    if (tid == 0) offsets[n] = carry;
}

__global__ void scatter_edges(const int* __restrict__ row, const int* __restrict__ col,
                              const float* __restrict__ dis, const int* __restrict__ offsets,
                              int* __restrict__ cursor, int* __restrict__ row_sorted,
                              float* __restrict__ ew_sorted, int E) {
    int e = blockIdx.x * 256 + threadIdx.x;
    if (e >= E) return;
    int c = col[e], r = row[e];
    int pos = offsets[c] + atomicAdd(&cursor[c], 1);
    row_sorted[pos] = r;
    ew_sorted[pos] = dis[c] * dis[r];
}

// ---------------- Graph propagation (CSR gather, bf16 rows, fp32 accum) ----------------
__global__ __launch_bounds__(128) void prop_b(const int* __restrict__ offsets,
                                              const int* __restrict__ row_sorted,
                                              const float* __restrict__ ew_sorted,
                                              const bf16_t* __restrict__ in,
                                              bf16_t* __restrict__ out) {
    int c = blockIdx.x;
    int ch = threadIdx.x;
    int s = offsets[c], e = offsets[c + 1];
    float acc = 0.0f;
    int i = s;
    for (; i + 1 < e; i += 2) {
        int r0 = row_sorted[i], r1 = row_sorted[i + 1];
        float w0 = ew_sorted[i], w1 = ew_sorted[i + 1];
        acc += w0 * (float)in[((size_t)r0 << 7) + ch] + w1 * (float)in[((size_t)r1 << 7) + ch];
    }
    if (i < e) acc += ew_sorted[i] * (float)in[((size_t)row_sorted[i] << 7) + ch];
    out[((size_t)c << 7) + ch] = (bf16_t)acc;
}

// ---------------- Weight transpose + bf16 convert: dst[n][k] = src[k][n] ----------------
__global__ void wcvt(const float* __restrict__ src, bf16_t* __restrict__ dst, int Ktot) {
    int i = blockIdx.x * 256 + threadIdx.x;
    if (i >= Ktot * 128) return;
    int k = i >> 7;
    int n = i & 127;
    dst[(size_t)n * Ktot + k] = (bf16_t)src[i];
}

// ---------------- A-fragment loaders ----------------
__device__ inline bf16x8 loadA(const float* ap) {
    float4 a0 = *(const float4*)ap;
    float4 a1 = *(const float4*)(ap + 4);
    bf16x8 f;
    f[0] = (bf16_t)a0.x; f[1] = (bf16_t)a0.y; f[2] = (bf16_t)a0.z; f[3] = (bf16_t)a0.w;
    f[4] = (bf16_t)a1.x; f[5] = (bf16_t)a1.y; f[6] = (bf16_t)a1.z; f[7] = (bf16_t)a1.w;
    return f;
}
__device__ inline bf16x8 loadA(const bf16_t* ap) { return *(const bf16x8*)ap; }

// ---------------- MFMA GEMM (K=128): out[N,128] = A[N,128] @ W (+bias)(norm)(/den) ----------------
// Wt pre-transposed bf16: Wt[n][k]
template <typename T, bool NORM>
__global__ __launch_bounds__(256) void gemm128s(const T* __restrict__ A,
                                                const bf16_t* __restrict__ Wt,
                                                const float* __restrict__ bias,
                                                const float* __restrict__ den,
                                                float* __restrict__ out,
                                                bf16_t* __restrict__ outb, int N) {
    int wave = threadIdx.x >> 6;
    int lane = threadIdx.x & 63;
    int quad = lane >> 4;
    int l16 = lane & 15;
    int m0 = blockIdx.x * 64 + wave * 16;
    int arow = m0 + l16;

    f32x4 acc[8] = {};
    #pragma unroll
    for (int kc = 0; kc < 128; kc += 32) {
        bf16x8 afrag = {};
        if (arow < N) afrag = loadA(A + ((size_t)arow << 7) + kc + quad * 8);
        #pragma unroll
        for (int t = 0; t < 8; t++) {
            const bf16_t* bp = Wt + (size_t)(t * 16 + l16) * 128 + kc + quad * 8;
            acc[t] = __builtin_amdgcn_mfma_f32_16x16x32_bf16(afrag, *(const bf16x8*)bp, acc[t],
                                                             0, 0, 0);
        }
    }
    float vals[8][4];
    #pragma unroll
    for (int t = 0; t < 8; t++) {
        float b = bias ? bias[t * 16 + l16] : 0.0f;
        #pragma unroll
        for (int r = 0; r < 4; r++) vals[t][r] = acc[t][r] + b;
    }
    if (NORM) {
        #pragma unroll
        for (int r = 0; r < 4; r++) {
            float p = 0.0f;
            #pragma unroll
            for (int t = 0; t < 8; t++) p += vals[t][r] * vals[t][r];
            p += __shfl_xor(p, 1);
            p += __shfl_xor(p, 2);
            p += __shfl_xor(p, 4);
            p += __shfl_xor(p, 8);
            float inv = rsqrtf(p);
            #pragma unroll
            for (int t = 0; t < 8; t++) vals[t][r] *= inv;
        }
    }
    #pragma unroll
    for (int r = 0; r < 4; r++) {
        int rr = m0 + quad * 4 + r;
        if (rr >= N) continue;
        float dinv = den ? (1.0f / den[rr]) : 1.0f;
        #pragma unroll
        for (int t = 0; t < 8; t++) {
            int c = t * 16 + l16;
            float v = vals[t][r] * dinv;
            if (out) out[((size_t)rr << 7) + c] = v;
            if (outb) outb[((size_t)rr << 7) + c] = (bf16_t)v;
        }
    }
}

// ---------------- MFMA GEMM (K=640): hn = cat(x1,h,p1,p2,p3)@Wfc + bias + res ----------------
__global__ __launch_bounds__(256) void gemm_fc(
    const bf16_t* __restrict__ s0, const bf16_t* __restrict__ s1, const bf16_t* __restrict__ s2,
    const bf16_t* __restrict__ s3, const bf16_t* __restrict__ s4,
    const bf16_t* __restrict__ Wt, const float* __restrict__ bias,
    const float* __restrict__ res, float* __restrict__ out, int N) {
    const bf16_t* srcs[5] = {s0, s1, s2, s3, s4};
    int wave = threadIdx.x >> 6;
    int lane = threadIdx.x & 63;
    int quad = lane >> 4;
    int l16 = lane & 15;
    int m0 = blockIdx.x * 64 + wave * 16;
    int arow = m0 + l16;

    f32x4 acc[8] = {};
    #pragma unroll
    for (int s = 0; s < 5; s++) {
        const bf16_t* As = srcs[s];
        #pragma unroll
        for (int k2 = 0; k2 < 128; k2 += 32) {
            bf16x8 afrag = {};
            if (arow < N) afrag = *(const bf16x8*)(As + ((size_t)arow << 7) + k2 + quad * 8);
            int kc = s * 128 + k2;
            #pragma unroll
            for (int t = 0; t < 8; t++) {
                const bf16_t* bp = Wt + (size_t)(t * 16 + l16) * 640 + kc + quad * 8;
                acc[t] = __builtin_amdgcn_mfma_f32_16x16x32_bf16(afrag, *(const bf16x8*)bp,
                                                                 acc[t], 0, 0, 0);
            }
        }
    }
    #pragma unroll
    for (int r = 0; r < 4; r++) {
        int rr = m0 + quad * 4 + r;
        if (rr >= N) continue;
        #pragma unroll
        for (int t = 0; t < 8; t++) {
            int c = t * 16 + l16;
            float v = acc[t][r] + bias[c] + res[((size_t)rr << 7) + c];
            out[((size_t)rr << 7) + c] = v;
        }
    }
}

// ---------------- kvs via MFMA: kvs[m][d] = sum_n kn[n][m]*v[n][d]; + ksum, vsum ----------------
__global__ __launch_bounds__(256) void kvs_mfma(const bf16_t* __restrict__ kn,
                                                const bf16_t* __restrict__ v,
                                                float* __restrict__ kvs,
                                                float* __restrict__ ksum,
                                                float* __restrict__ vsum, int N) {
    __shared__ bf16_t Lk[32][132];
    __shared__ bf16_t Lv[32][132];
    __shared__ float lred[256];
    int t = threadIdx.x;
    int wave = t >> 6, lane = t & 63, quad = lane >> 4, l16 = lane & 15;
    int tr = t >> 4, tc = (t & 15) * 8;
    int mbase = wave * 32;
    f32x4 acc[2][8] = {};
    float ks[8] = {}, vs[8] = {};
    for (int base = blockIdx.x * 32; base < N; base += gridDim.x * 32) {
        __syncthreads();
        #pragma unroll
        for (int hh = 0; hh < 2; hh++) {
            int r = hh * 16 + tr;
            int rowi = base + r;
            bf16x8 ck = {}, cv = {};
            if (rowi < N) {
                ck = *(const bf16x8*)(kn + ((size_t)rowi << 7) + tc);
                cv = *(const bf16x8*)(v + ((size_t)rowi << 7) + tc);
            }
            bf16x4 klo, khi, vlo, vhi;
            #pragma unroll
            for (int j = 0; j < 4; j++) {
                klo[j] = ck[j]; khi[j] = ck[j + 4];
                vlo[j] = cv[j]; vhi[j] = cv[j + 4];
                ks[j] += (float)ck[j]; ks[j + 4] += (float)ck[j + 4];
                vs[j] += (float)cv[j]; vs[j + 4] += (float)cv[j + 4];
            }
            *(bf16x4*)&Lk[r][tc] = klo;
            *(bf16x4*)&Lk[r][tc + 4] = khi;
            *(bf16x4*)&Lv[r][tc] = vlo;
            *(bf16x4*)&Lv[r][tc + 4] = vhi;
        }
        __syncthreads();
        bf16x8 af[2], bfr[8];
        #pragma unroll
        for (int mt = 0; mt < 2; mt++)
            #pragma unroll
            for (int j = 0; j < 8; j++) af[mt][j] = Lk[quad * 8 + j][mbase + mt * 16 + l16];
        #pragma unroll
        for (int tt = 0; tt < 8; tt++)
            #pragma unroll
            for (int j = 0; j < 8; j++) bfr[tt][j] = Lv[quad * 8 + j][tt * 16 + l16];
        #pragma unroll
        for (int mt = 0; mt < 2; mt++)
            #pragma unroll
            for (int tt = 0; tt < 8; tt++)
                acc[mt][tt] = __builtin_amdgcn_mfma_f32_16x16x32_bf16(af[mt], bfr[tt],
                                                                      acc[mt][tt], 0, 0, 0);
    }
    #pragma unroll
    for (int mt = 0; mt < 2; mt++)
        #pragma unroll
        for (int tt = 0; tt < 8; tt++)
            #pragma unroll
            for (int r = 0; r < 4; r++) {
                int m = mbase + mt * 16 + quad * 4 + r;
                int d = tt * 16 + l16;
                atomicAdd(&kvs[m * HD + d], acc[mt][tt][r]);
            }
    lred[t] = 0.0f;
    __syncthreads();
    #pragma unroll
    for (int j = 0; j < 8; j++) {
        atomicAdd(&lred[tc + j], ks[j]);
        atomicAdd(&lred[128 + tc + j], vs[j]);
    }
    __syncthreads();
    if (t < 128) {
        atomicAdd(&ksum[t], lred[t]);
        atomicAdd(&vsum[t], lred[t + 128]);
    }
}

// ---------------- BatchNorm ----------------
__global__ __launch_bounds__(256) void bn_stats(const float* __restrict__ z,
                                                float* __restrict__ sums,
                                                float* __restrict__ sumsq, int N) {
    int ch = threadIdx.x & 127;
    int rw = threadIdx.x >> 7;
    float s = 0.0f, ss = 0.0f;
    for (int n = blockIdx.x * 2 + rw; n < N; n += gridDim.x * 2) {
        float v = z[(size_t)n * HD + ch];
        s += v;
        ss += v * v;
    }
    __shared__ float Ls[256], Lss[256];
    Ls[threadIdx.x] = s;
    Lss[threadIdx.x] = ss;
    __syncthreads();
    if (rw == 0) {
        atomicAdd(&sums[ch], s + Ls[threadIdx.x + 128]);
        atomicAdd(&sumsq[ch], ss + Lss[threadIdx.x + 128]);
    }
}

__global__ void bn_finalize(const float* __restrict__ sums, const float* __restrict__ sumsq,
                            const float* __restrict__ g, const float* __restrict__ b,
                            float* __restrict__ scale, float* __restrict__ shift, int N) {
    int ch = threadIdx.x;
    float m = sums[ch] / (float)N;
    float var = sumsq[ch] / (float)N - m * m;
    float sc = g[ch] * rsqrtf(var + EPS_BN);
    scale[ch] = sc;
    shift[ch] = b[ch] - m * sc;
}

__global__ void bn_apply(const float4* __restrict__ z, float4* __restrict__ h,
                         bf16_t* __restrict__ hb, const float* __restrict__ scale,
                         const float* __restrict__ shift, int n4) {
    int i = blockIdx.x * blockDim.x + threadIdx.x;
    if (i >= n4) return;
    int c4 = i & 31;
    float4 zv = z[i];
    float4 sc = ((const float4*)scale)[c4];
    float4 sh = ((const float4*)shift)[c4];
    float4 hv;
    hv.x = fmaxf(zv.x * sc.x + sh.x, 0.0f);
    hv.y = fmaxf(zv.y * sc.y + sh.y, 0.0f);
    hv.z = fmaxf(zv.z * sc.z + sh.z, 0.0f);
    hv.w = fmaxf(zv.w * sc.w + sh.w, 0.0f);
    h[i] = hv;
    bf16x4 hb4;
    hb4[0] = (bf16_t)hv.x; hb4[1] = (bf16_t)hv.y; hb4[2] = (bf16_t)hv.z; hb4[3] = (bf16_t)hv.w;
    *(bf16x4*)(hb + (size_t)i * 4) = hb4;
}

// ---------------- den ----------------
__global__ __launch_bounds__(256) void den_kernel(const float* __restrict__ qn,
                                                  const float* __restrict__ ksum,
                                                  float* __restrict__ den, int N) {
    int lane = threadIdx.x & 63;
    int wv = threadIdx.x >> 6;
    int n = blockIdx.x * 4 + wv;
    if (n >= N) return;
    float2 qv = *(const float2*)(qn + (size_t)n * HD + lane * 2);
    float2 kv = *(const float2*)(ksum + lane * 2);
    float s = qv.x * kv.x + qv.y * kv.y;
    #pragma unroll
    for (int o = 32; o > 0; o >>= 1) s += __shfl_down(s, o, 64);
    if (lane == 0) den[n] = s + (float)NN;
}

// ---------------- Output GEMM [N,128]@[128,40] ----------------
__global__ void out_gemm(const float* __restrict__ h, const float* __restrict__ W,
                         const float* __restrict__ b, float* __restrict__ out, int N) {
    int idx = blockIdx.x * blockDim.x + threadIdx.x;
    if (idx >= N * 40) return;
    int n = idx / 40;
    int j = idx - n * 40;
    float acc = b[j];
    const float* hr = h + (size_t)n * HD;
    for (int k = 0; k < HD; k++) acc += hr[k] * W[k * 40 + j];
    out[idx] = acc;
}

extern "C" void kernel_launch(void* const* d_in, const int* in_sizes, int n_in,
                              void* d_out, int out_size, void* d_ws, size_t ws_size,
                              hipStream_t stream) {
    const float* x = (const float*)d_in[0];
    const int* eidx = (const int*)d_in[1];
    const float* W_in = (const float*)d_in[2];
    const float* b_in = (const float*)d_in[3];
    const float* Wq = (const float*)d_in[4];
    const float* bq = (const float*)d_in[5];
    const float* Wk = (const float*)d_in[6];
    const float* bk = (const float*)d_in[7];
    const float* Wfc = (const float*)d_in[8];
    const float* bfc = (const float*)d_in[9];
    const float* W_out = (const float*)d_in[10];
    const float* b_out = (const float*)d_in[11];
    const float* bn_g = (const float*)d_in[12];
    const float* bn_b = (const float*)d_in[13];
    float* out = (float*)d_out;

    const int N = NN, E = NE;
    const int* rowp = eidx;
    const int* colp = eidx + E;

    char* ws = (char*)d_ws;
    size_t off = 0;
    auto nxt = [&](size_t bytes) -> void* {
        void* p = ws + off;
        off += (bytes + 255) & ~(size_t)255;
        return p;
    };
    int* counts = (int*)nxt((size_t)N * 4);
    int* offsets = (int*)nxt((size_t)(N + 1) * 4);
    int* cursor = (int*)nxt((size_t)N * 4);
    int* row_sorted = (int*)nxt((size_t)E * 4);
    float* ew_sorted = (float*)nxt((size_t)E * 4);
    float* dis = (float*)nxt((size_t)N * 4);
    float* den = (float*)nxt((size_t)N * 4);
    float* kvs = (float*)nxt((size_t)HD * HD * 4);  // + ksum + vsum contiguous
    float* ksum = (float*)nxt((size_t)HD * 4);
    float* vsum = (float*)nxt((size_t)HD * 4);
    float* bnsum = (float*)nxt((size_t)HD * 4);  // + bnsumsq contiguous
    float* bnsumsq = (float*)nxt((size_t)HD * 4);
    float* bnscale = (float*)nxt((size_t)HD * 4);
    float* bnshift = (float*)nxt((size_t)HD * 4);
    float* h = (float*)nxt((size_t)N * HD * 4);
    float* hn = (float*)nxt((size_t)N * HD * 4);
    float* qb = (float*)nxt((size_t)N * HD * 4);
    // bf16 activations
    bf16_t* hb = (bf16_t*)nxt((size_t)N * HD * 2);
    bf16_t* p1b = (bf16_t*)nxt((size_t)N * HD * 2);
    bf16_t* p2b = (bf16_t*)nxt((size_t)N * HD * 2);
    bf16_t* p3b = (bf16_t*)nxt((size_t)N * HD * 2);
    bf16_t* knb = (bf16_t*)nxt((size_t)N * HD * 2);
    bf16_t* x1b = (bf16_t*)nxt((size_t)N * HD * 2);
    // bf16 transposed weights
    bf16_t* Wt_in = (bf16_t*)nxt((size_t)HD * HD * 2);
    bf16_t* Wt_q = (bf16_t*)nxt((size_t)2 * HD * HD * 2);
    bf16_t* Wt_k = (bf16_t*)nxt((size_t)2 * HD * HD * 2);
    bf16_t* Wt_fc = (bf16_t*)nxt((size_t)2 * 640 * HD * 2);
    bf16_t* kvsT = (bf16_t*)nxt((size_t)HD * HD * 2);

    const int GB = (N + 63) / 64;

    // ---- CSR build ----
    hipMemsetAsync(counts, 0, (size_t)N * 4, stream);
    count_edges<<<(E + 255) / 256, 256, 0, stream>>>(colp, counts, E);
    dis_kernel<<<(N + 255) / 256, 256, 0, stream>>>(counts, dis, N);
    scan_kernel<<<1, 1024, 0, stream>>>(counts, offsets, N);
    hipMemsetAsync(cursor, 0, (size_t)N * 4, stream);
    scatter_edges<<<(E + 255) / 256, 256, 0, stream>>>(rowp, colp, dis, offsets, cursor,
                                                       row_sorted, ew_sorted, E);

    // ---- weight transposes ----
    wcvt<<<64, 256, 0, stream>>>(W_in, Wt_in, HD);
    wcvt<<<64, 256, 0, stream>>>(Wq, Wt_q, HD);
    wcvt<<<64, 256, 0, stream>>>(Wq + HD * HD, Wt_q + HD * HD, HD);
    wcvt<<<64, 256, 0, stream>>>(Wk, Wt_k, HD);
    wcvt<<<64, 256, 0, stream>>>(Wk + HD * HD, Wt_k + HD * HD, HD);
    wcvt<<<320, 256, 0, stream>>>(Wfc, Wt_fc, 640);
    wcvt<<<320, 256, 0, stream>>>(Wfc + 640 * HD, Wt_fc + 640 * HD, 640);

    // ---- input layer ----
    gemm128s<float, false><<<GB, 256, 0, stream>>>(x, Wt_in, b_in, nullptr, hn, nullptr, N);
    hipMemsetAsync(bnsum, 0, 1024, stream);
    bn_stats<<<400, 256, 0, stream>>>(hn, bnsum, bnsumsq, N);
    bn_finalize<<<1, 128, 0, stream>>>(bnsum, bnsumsq, bn_g, bn_b, bnscale, bnshift, N);
    bn_apply<<<(N * 32 + 255) / 256, 256, 0, stream>>>((const float4*)hn, (float4*)h, hb,
                                                       bnscale, bnshift, N * 32);

    for (int i = 0; i < 2; i++) {
        const float* bq_i = bq + (size_t)i * HD;
        const float* bk_i = bk + (size_t)i * HD;
        const float* bfc_i = bfc + (size_t)i * HD;
        bf16_t* Wt_q_i = Wt_q + (size_t)i * HD * HD;
        bf16_t* Wt_k_i = Wt_k + (size_t)i * HD * HD;
        bf16_t* Wt_fc_i = Wt_fc + (size_t)i * 640 * HD;

        // K-hop diffusion (bf16)
        prop_b<<<N, 128, 0, stream>>>(offsets, row_sorted, ew_sorted, hb, p1b);
        prop_b<<<N, 128, 0, stream>>>(offsets, row_sorted, ew_sorted, p1b, p2b);
        prop_b<<<N, 128, 0, stream>>>(offsets, row_sorted, ew_sorted, p2b, p3b);

        // attention: q (fp32, normalized), kn (bf16, normalized)
        gemm128s<bf16_t, true><<<GB, 256, 0, stream>>>(hb, Wt_q_i, bq_i, nullptr, qb, nullptr, N);
        gemm128s<bf16_t, true><<<GB, 256, 0, stream>>>(hb, Wt_k_i, bk_i, nullptr, nullptr, knb, N);
        hipMemsetAsync(kvs, 0, 66560, stream);  // kvs + ksum + vsum
        kvs_mfma<<<256, 256, 0, stream>>>(knb, hb, kvs, ksum, vsum, N);
        den_kernel<<<(N + 3) / 4, 256, 0, stream>>>(qb, ksum, den, N);
        wcvt<<<64, 256, 0, stream>>>(kvs, kvsT, HD);
        // x1 = (qn @ kvs + vsum)/den -> bf16
        gemm128s<float, false><<<GB, 256, 0, stream>>>(qb, kvsT, vsum, den, nullptr, x1b, N);

        // z = cat(x1,h,p1,p2,p3) @ Wfc + bfc + h
        gemm_fc<<<GB, 256, 0, stream>>>(x1b, hb, p1b, p2b, p3b, Wt_fc_i, bfc_i, h, hn, N);
        hipMemsetAsync(bnsum, 0, 1024, stream);
        bn_stats<<<400, 256, 0, stream>>>(hn, bnsum, bnsumsq, N);
        bn_finalize<<<1, 128, 0, stream>>>(bnsum, bnsumsq, bn_g + (size_t)(i + 1) * HD,
                                           bn_b + (size_t)(i + 1) * HD, bnscale, bnshift, N);
        bn_apply<<<(N * 32 + 255) / 256, 256, 0, stream>>>((const float4*)hn, (float4*)h, hb,
                                                           bnscale, bnshift, N * 32);
    }

    out_gemm<<<(N * 40 + 255) / 256, 256, 0, stream>>>(h, W_out, b_out, out, N);
}

// Round 4
// 964.814 us; speedup vs baseline: 2.1140x; 1.2378x over previous
//
#include <hip/hip_runtime.h>
#include <hip/hip_bf16.h>
#include <math.h>

#define NN 50000
#define NE 800000
#define HD 128
#define EPS_BN 1e-5f

typedef __bf16 bf16_t;
typedef bf16_t bf16x8 __attribute__((ext_vector_type(8)));
typedef bf16_t bf16x4 __attribute__((ext_vector_type(4)));
typedef float f32x4 __attribute__((ext_vector_type(4)));

// ---------------- CSR build ----------------
__global__ void count_edges(const int* __restrict__ col, int* __restrict__ counts, int E) {
    int e = blockIdx.x * 256 + threadIdx.x;
    if (e >= E) return;
    atomicAdd(&counts[col[e]], 1);
}

__global__ void dis_kernel(const int* __restrict__ counts, float* __restrict__ dis, int N) {
    int i = blockIdx.x * 256 + threadIdx.x;
    if (i >= N) return;
    int c = counts[i];
    dis[i] = (c > 0) ? rsqrtf((float)c) : 0.0f;
}

__global__ __launch_bounds__(1024) void scan_kernel(const int* __restrict__ counts,
                                                    int* __restrict__ offsets, int n) {
    __shared__ int wsum[16];
    int tid = threadIdx.x;
    int lane = tid & 63;
    int w = tid >> 6;
    int carry = 0;
    for (int base = 0; base < n; base += 1024) {
        int i = base + tid;
        int v = (i < n) ? counts[i] : 0;
        int x = v;
        #pragma unroll
        for (int o = 1; o < 64; o <<= 1) {
            int t = __shfl_up(x, o, 64);
            if (lane >= o) x += t;
        }
        if (lane == 63) wsum[w] = x;
        __syncthreads();
        if (w == 0 && lane < 16) {
            int y = wsum[lane];
            #pragma unroll
            for (int o = 1; o < 16; o <<= 1) {
                int t = __shfl_up(y, o, 64);
                if (lane >= o) y += t;
            }
            wsum[lane] = y;
        }
        __syncthreads();
        int wpre = (w > 0) ? wsum[w - 1] : 0;
        int incl = carry + wpre + x;
        if (i < n) offsets[i] = incl - v;  // exclusive
        carry += wsum[15];
        __syncthreads();
    }
    if (tid == 0) offsets[n] = carry;
}

__global__ void scatter_edges(const int* __restrict__ row, const int* __restrict__ col,
                              const float* __restrict__ dis, const int* __restrict__ offsets,
                              int* __restrict__ cursor, int* __restrict__ row_sorted,
                              float* __restrict__ ew_sorted, int E) {
    int e = blockIdx.x * 256 + threadIdx.x;
    if (e >= E) return;
    int c = col[e], r = row[e];
    int pos = offsets[c] + atomicAdd(&cursor[c], 1);
    row_sorted[pos] = r;
    ew_sorted[pos] = dis[c] * dis[r];
}

// ---------------- Graph propagation (CSR gather, bf16 rows, fp32 accum) ----------------
__global__ __launch_bounds__(128) void prop_b(const int* __restrict__ offsets,
                                              const int* __restrict__ row_sorted,
                                              const float* __restrict__ ew_sorted,
                                              const bf16_t* __restrict__ in,
                                              bf16_t* __restrict__ out) {
    int c = blockIdx.x;
    int ch = threadIdx.x;
    int s = offsets[c], e = offsets[c + 1];
    float acc = 0.0f;
    int i = s;
    for (; i + 3 < e; i += 4) {
        int r0 = row_sorted[i], r1 = row_sorted[i + 1];
        int r2 = row_sorted[i + 2], r3 = row_sorted[i + 3];
        float w0 = ew_sorted[i], w1 = ew_sorted[i + 1];
        float w2 = ew_sorted[i + 2], w3 = ew_sorted[i + 3];
        float a0 = (float)in[((size_t)r0 << 7) + ch];
        float a1 = (float)in[((size_t)r1 << 7) + ch];
        float a2 = (float)in[((size_t)r2 << 7) + ch];
        float a3 = (float)in[((size_t)r3 << 7) + ch];
        acc += w0 * a0 + w1 * a1 + w2 * a2 + w3 * a3;
    }
    for (; i < e; i++)
        acc += ew_sorted[i] * (float)in[((size_t)row_sorted[i] << 7) + ch];
    out[((size_t)c << 7) + ch] = (bf16_t)acc;
}

// ---------------- Weight packing: fragment order ----------------
// src: fp32 W[k][n] (Ktot x 128). dst: for tile t (n-block), chunk kc (K-block of 32):
// dst[((t*nkc+kc)*64+lane)*8 + j] = W[kc*32 + (lane>>4)*8 + j][t*16 + (lane&15)]
__global__ void wcvt_frag(const float* __restrict__ W, bf16_t* __restrict__ Wp, int nkc) {
    int p = blockIdx.x * 256 + threadIdx.x;
    if (p >= 8 * nkc * 64) return;
    int lane = p & 63;
    int tk = p >> 6;
    int kc = tk % nkc;
    int t = tk / nkc;
    int n = t * 16 + (lane & 15);
    int k0 = kc * 32 + (lane >> 4) * 8;
    bf16x8 f;
    #pragma unroll
    for (int j = 0; j < 8; j++) f[j] = (bf16_t)W[(size_t)(k0 + j) * 128 + n];
    *(bf16x8*)(Wp + (size_t)p * 8) = f;
}

// ---------------- A-fragment loaders ----------------
__device__ inline bf16x8 loadA(const float* ap) {
    float4 a0 = *(const float4*)ap;
    float4 a1 = *(const float4*)(ap + 4);
    bf16x8 f;
    f[0] = (bf16_t)a0.x; f[1] = (bf16_t)a0.y; f[2] = (bf16_t)a0.z; f[3] = (bf16_t)a0.w;
    f[4] = (bf16_t)a1.x; f[5] = (bf16_t)a1.y; f[6] = (bf16_t)a1.z; f[7] = (bf16_t)a1.w;
    return f;
}
__device__ inline bf16x8 loadA(const bf16_t* ap) { return *(const bf16x8*)ap; }

// ---------------- MFMA GEMM (K=128): out[N,128] = A[N,128] @ W (+bias)(norm) ----------------
// Wp: fragment-packed (nkc=4)
template <typename T, bool NORM>
__global__ __launch_bounds__(256) void gemm128s(const T* __restrict__ A,
                                                const bf16_t* __restrict__ Wp,
                                                const float* __restrict__ bias,
                                                float* __restrict__ out,
                                                bf16_t* __restrict__ outb, int N) {
    int wave = threadIdx.x >> 6;
    int lane = threadIdx.x & 63;
    int quad = lane >> 4;
    int l16 = lane & 15;
    int m0 = blockIdx.x * 64 + wave * 16;
    int arow = m0 + l16;

    f32x4 acc[8] = {};
    #pragma unroll
    for (int kc = 0; kc < 4; kc++) {
        bf16x8 afrag = {};
        if (arow < N) afrag = loadA(A + ((size_t)arow << 7) + kc * 32 + quad * 8);
        #pragma unroll
        for (int t = 0; t < 8; t++) {
            const bf16_t* bp = Wp + (size_t)(((t * 4 + kc) * 64) + lane) * 8;
            acc[t] = __builtin_amdgcn_mfma_f32_16x16x32_bf16(afrag, *(const bf16x8*)bp, acc[t],
                                                             0, 0, 0);
        }
    }
    float vals[8][4];
    #pragma unroll
    for (int t = 0; t < 8; t++) {
        float b = bias ? bias[t * 16 + l16] : 0.0f;
        #pragma unroll
        for (int r = 0; r < 4; r++) vals[t][r] = acc[t][r] + b;
    }
    if (NORM) {
        #pragma unroll
        for (int r = 0; r < 4; r++) {
            float p = 0.0f;
            #pragma unroll
            for (int t = 0; t < 8; t++) p += vals[t][r] * vals[t][r];
            p += __shfl_xor(p, 1);
            p += __shfl_xor(p, 2);
            p += __shfl_xor(p, 4);
            p += __shfl_xor(p, 8);
            float inv = rsqrtf(p);
            #pragma unroll
            for (int t = 0; t < 8; t++) vals[t][r] *= inv;
        }
    }
    #pragma unroll
    for (int r = 0; r < 4; r++) {
        int rr = m0 + quad * 4 + r;
        if (rr >= N) continue;
        #pragma unroll
        for (int t = 0; t < 8; t++) {
            int c = t * 16 + l16;
            float v = vals[t][r];
            if (out) out[((size_t)rr << 7) + c] = v;
            if (outb) outb[((size_t)rr << 7) + c] = (bf16_t)v;
        }
    }
}

// ---------------- fc GEMM with folded attention ----------------
// z = (qn@M1 + bvec)/den + [h,p1,p2,p3]@W[128:640] + bfc + res
// WpM1: frag-packed M1 (nkc=4); Wp: frag-packed full Wfc (nkc=20), chunks 4..19 used
__global__ __launch_bounds__(256) void gemm_fc(
    const bf16_t* __restrict__ qn, const bf16_t* __restrict__ s1, const bf16_t* __restrict__ s2,
    const bf16_t* __restrict__ s3, const bf16_t* __restrict__ s4,
    const bf16_t* __restrict__ WpM1, const bf16_t* __restrict__ Wp,
    const float* __restrict__ bvec, const float* __restrict__ bfc,
    const float* __restrict__ den, const float* __restrict__ res,
    float* __restrict__ out, int N) {
    const bf16_t* srcs[4] = {s1, s2, s3, s4};
    int wave = threadIdx.x >> 6;
    int lane = threadIdx.x & 63;
    int quad = lane >> 4;
    int l16 = lane & 15;
    int m0 = blockIdx.x * 64 + wave * 16;
    int arow = m0 + l16;

    f32x4 accA[8] = {};
    f32x4 accB[8] = {};
    // attention source (qn) against M1
    #pragma unroll
    for (int kc = 0; kc < 4; kc++) {
        bf16x8 afrag = {};
        if (arow < N) afrag = *(const bf16x8*)(qn + ((size_t)arow << 7) + kc * 32 + quad * 8);
        #pragma unroll
        for (int t = 0; t < 8; t++) {
            const bf16_t* bp = WpM1 + (size_t)(((t * 4 + kc) * 64) + lane) * 8;
            accA[t] = __builtin_amdgcn_mfma_f32_16x16x32_bf16(afrag, *(const bf16x8*)bp, accA[t],
                                                              0, 0, 0);
        }
    }
    // gnn sources against Wfc[128:640]
    #pragma unroll
    for (int s = 0; s < 4; s++) {
        const bf16_t* As = srcs[s];
        #pragma unroll
        for (int k2 = 0; k2 < 4; k2++) {
            bf16x8 afrag = {};
            if (arow < N) afrag = *(const bf16x8*)(As + ((size_t)arow << 7) + k2 * 32 + quad * 8);
            int kcidx = (s + 1) * 4 + k2;
            #pragma unroll
            for (int t = 0; t < 8; t++) {
                const bf16_t* bp = Wp + (size_t)(((t * 20 + kcidx) * 64) + lane) * 8;
                accB[t] = __builtin_amdgcn_mfma_f32_16x16x32_bf16(afrag, *(const bf16x8*)bp,
                                                                  accB[t], 0, 0, 0);
            }
        }
    }
    #pragma unroll
    for (int r = 0; r < 4; r++) {
        int rr = m0 + quad * 4 + r;
        if (rr >= N) continue;
        float dinv = 1.0f / den[rr];
        #pragma unroll
        for (int t = 0; t < 8; t++) {
            int c = t * 16 + l16;
            float v = (accA[t][r] + bvec[c]) * dinv + accB[t][r] + bfc[c] +
                      res[((size_t)rr << 7) + c];
            out[((size_t)rr << 7) + c] = v;
        }
    }
}

// ---------------- kvs via MFMA ----------------
__global__ __launch_bounds__(256) void kvs_mfma(const bf16_t* __restrict__ kn,
                                                const bf16_t* __restrict__ v,
                                                float* __restrict__ kvs,
                                                float* __restrict__ ksum,
                                                float* __restrict__ vsum, int N) {
    __shared__ bf16_t Lk[32][132];
    __shared__ bf16_t Lv[32][132];
    __shared__ float lred[256];
    int t = threadIdx.x;
    int wave = t >> 6, lane = t & 63, quad = lane >> 4, l16 = lane & 15;
    int tr = t >> 4, tc = (t & 15) * 8;
    int mbase = wave * 32;
    f32x4 acc[2][8] = {};
    float ks[8] = {}, vs[8] = {};
    for (int base = blockIdx.x * 32; base < N; base += gridDim.x * 32) {
        __syncthreads();
        #pragma unroll
        for (int hh = 0; hh < 2; hh++) {
            int r = hh * 16 + tr;
            int rowi = base + r;
            bf16x8 ck = {}, cv = {};
            if (rowi < N) {
                ck = *(const bf16x8*)(kn + ((size_t)rowi << 7) + tc);
                cv = *(const bf16x8*)(v + ((size_t)rowi << 7) + tc);
            }
            bf16x4 klo, khi, vlo, vhi;
            #pragma unroll
            for (int j = 0; j < 4; j++) {
                klo[j] = ck[j]; khi[j] = ck[j + 4];
                vlo[j] = cv[j]; vhi[j] = cv[j + 4];
                ks[j] += (float)ck[j]; ks[j + 4] += (float)ck[j + 4];
                vs[j] += (float)cv[j]; vs[j + 4] += (float)cv[j + 4];
            }
            *(bf16x4*)&Lk[r][tc] = klo;
            *(bf16x4*)&Lk[r][tc + 4] = khi;
            *(bf16x4*)&Lv[r][tc] = vlo;
            *(bf16x4*)&Lv[r][tc + 4] = vhi;
        }
        __syncthreads();
        bf16x8 af[2], bfr[8];
        #pragma unroll
        for (int mt = 0; mt < 2; mt++)
            #pragma unroll
            for (int j = 0; j < 8; j++) af[mt][j] = Lk[quad * 8 + j][mbase + mt * 16 + l16];
        #pragma unroll
        for (int tt = 0; tt < 8; tt++)
            #pragma unroll
            for (int j = 0; j < 8; j++) bfr[tt][j] = Lv[quad * 8 + j][tt * 16 + l16];
        #pragma unroll
        for (int mt = 0; mt < 2; mt++)
            #pragma unroll
            for (int tt = 0; tt < 8; tt++)
                acc[mt][tt] = __builtin_amdgcn_mfma_f32_16x16x32_bf16(af[mt], bfr[tt],
                                                                      acc[mt][tt], 0, 0, 0);
    }
    #pragma unroll
    for (int mt = 0; mt < 2; mt++)
        #pragma unroll
        for (int tt = 0; tt < 8; tt++)
            #pragma unroll
            for (int r = 0; r < 4; r++) {
                int m = mbase + mt * 16 + quad * 4 + r;
                int d = tt * 16 + l16;
                atomicAdd(&kvs[m * HD + d], acc[mt][tt][r]);
            }
    lred[t] = 0.0f;
    __syncthreads();
    #pragma unroll
    for (int j = 0; j < 8; j++) {
        atomicAdd(&lred[tc + j], ks[j]);
        atomicAdd(&lred[128 + tc + j], vs[j]);
    }
    __syncthreads();
    if (t < 128) {
        atomicAdd(&ksum[t], lred[t]);
        atomicAdd(&vsum[t], lred[t + 128]);
    }
}

// ---------------- M1 = kvs @ W0, bvec = vsum @ W0 ----------------
__global__ void m1_kernel(const float* __restrict__ kvs, const float* __restrict__ W0,
                          float* __restrict__ M1) {
    int idx = blockIdx.x * 256 + threadIdx.x;
    int m = idx >> 7;
    int c = idx & 127;
    float acc = 0.0f;
    for (int d = 0; d < 128; d += 4) {
        float4 k4 = *(const float4*)(kvs + m * 128 + d);
        acc += k4.x * W0[(d + 0) * 128 + c] + k4.y * W0[(d + 1) * 128 + c] +
               k4.z * W0[(d + 2) * 128 + c] + k4.w * W0[(d + 3) * 128 + c];
    }
    M1[idx] = acc;
}

__global__ void bvec_kernel(const float* __restrict__ vsum, const float* __restrict__ W0,
                            float* __restrict__ bvec) {
    int c = threadIdx.x;
    float acc = 0.0f;
    for (int d = 0; d < 128; d++) acc += vsum[d] * W0[d * 128 + c];
    bvec[c] = acc;
}

// ---------------- BatchNorm ----------------
__global__ __launch_bounds__(256) void bn_stats(const float* __restrict__ z,
                                                float* __restrict__ sums,
                                                float* __restrict__ sumsq, int N) {
    int ch = threadIdx.x & 127;
    int rw = threadIdx.x >> 7;
    float s = 0.0f, ss = 0.0f;
    for (int n = blockIdx.x * 2 + rw; n < N; n += gridDim.x * 2) {
        float v = z[(size_t)n * HD + ch];
        s += v;
        ss += v * v;
    }
    __shared__ float Ls[256], Lss[256];
    Ls[threadIdx.x] = s;
    Lss[threadIdx.x] = ss;
    __syncthreads();
    if (rw == 0) {
        atomicAdd(&sums[ch], s + Ls[threadIdx.x + 128]);
        atomicAdd(&sumsq[ch], ss + Lss[threadIdx.x + 128]);
    }
}

__global__ void bn_finalize(const float* __restrict__ sums, const float* __restrict__ sumsq,
                            const float* __restrict__ g, const float* __restrict__ b,
                            float* __restrict__ scale, float* __restrict__ shift, int N) {
    int ch = threadIdx.x;
    float m = sums[ch] / (float)N;
    float var = sumsq[ch] / (float)N - m * m;
    float sc = g[ch] * rsqrtf(var + EPS_BN);
    scale[ch] = sc;
    shift[ch] = b[ch] - m * sc;
}

__global__ void bn_apply(const float4* __restrict__ z, float4* __restrict__ h,
                         bf16_t* __restrict__ hb, const float* __restrict__ scale,
                         const float* __restrict__ shift, int n4) {
    int i = blockIdx.x * blockDim.x + threadIdx.x;
    if (i >= n4) return;
    int c4 = i & 31;
    float4 zv = z[i];
    float4 sc = ((const float4*)scale)[c4];
    float4 sh = ((const float4*)shift)[c4];
    float4 hv;
    hv.x = fmaxf(zv.x * sc.x + sh.x, 0.0f);
    hv.y = fmaxf(zv.y * sc.y + sh.y, 0.0f);
    hv.z = fmaxf(zv.z * sc.z + sh.z, 0.0f);
    hv.w = fmaxf(zv.w * sc.w + sh.w, 0.0f);
    h[i] = hv;
    bf16x4 hb4;
    hb4[0] = (bf16_t)hv.x; hb4[1] = (bf16_t)hv.y; hb4[2] = (bf16_t)hv.z; hb4[3] = (bf16_t)hv.w;
    *(bf16x4*)(hb + (size_t)i * 4) = hb4;
}

// ---------------- den ----------------
__global__ __launch_bounds__(256) void den_kernel(const float* __restrict__ qn,
                                                  const float* __restrict__ ksum,
                                                  float* __restrict__ den, int N) {
    int lane = threadIdx.x & 63;
    int wv = threadIdx.x >> 6;
    int n = blockIdx.x * 4 + wv;
    if (n >= N) return;
    float2 qv = *(const float2*)(qn + (size_t)n * HD + lane * 2);
    float2 kv = *(const float2*)(ksum + lane * 2);
    float s = qv.x * kv.x + qv.y * kv.y;
    #pragma unroll
    for (int o = 32; o > 0; o >>= 1) s += __shfl_down(s, o, 64);
    if (lane == 0) den[n] = s + (float)NN;
}

// ---------------- Output GEMM [N,128]@[128,40] ----------------
__global__ void out_gemm(const float* __restrict__ h, const float* __restrict__ W,
                         const float* __restrict__ b, float* __restrict__ out, int N) {
    int idx = blockIdx.x * blockDim.x + threadIdx.x;
    if (idx >= N * 40) return;
    int n = idx / 40;
    int j = idx - n * 40;
    float acc = b[j];
    const float* hr = h + (size_t)n * HD;
    for (int k = 0; k < HD; k++) acc += hr[k] * W[k * 40 + j];
    out[idx] = acc;
}

extern "C" void kernel_launch(void* const* d_in, const int* in_sizes, int n_in,
                              void* d_out, int out_size, void* d_ws, size_t ws_size,
                              hipStream_t stream) {
    const float* x = (const float*)d_in[0];
    const int* eidx = (const int*)d_in[1];
    const float* W_in = (const float*)d_in[2];
    const float* b_in = (const float*)d_in[3];
    const float* Wq = (const float*)d_in[4];
    const float* bq = (const float*)d_in[5];
    const float* Wk = (const float*)d_in[6];
    const float* bk = (const float*)d_in[7];
    const float* Wfc = (const float*)d_in[8];
    const float* bfc = (const float*)d_in[9];
    const float* W_out = (const float*)d_in[10];
    const float* b_out = (const float*)d_in[11];
    const float* bn_g = (const float*)d_in[12];
    const float* bn_b = (const float*)d_in[13];
    float* out = (float*)d_out;

    const int N = NN, E = NE;
    const int* rowp = eidx;
    const int* colp = eidx + E;

    char* ws = (char*)d_ws;
    size_t off = 0;
    auto nxt = [&](size_t bytes) -> void* {
        void* p = ws + off;
        off += (bytes + 255) & ~(size_t)255;
        return p;
    };
    int* counts = (int*)nxt((size_t)N * 4);
    int* offsets = (int*)nxt((size_t)(N + 1) * 4);
    int* cursor = (int*)nxt((size_t)N * 4);
    int* row_sorted = (int*)nxt((size_t)E * 4);
    float* ew_sorted = (float*)nxt((size_t)E * 4);
    float* dis = (float*)nxt((size_t)N * 4);
    float* den = (float*)nxt((size_t)N * 4);
    float* kvs = (float*)nxt((size_t)HD * HD * 4);  // + ksum + vsum contiguous
    float* ksum = (float*)nxt((size_t)HD * 4);
    float* vsum = (float*)nxt((size_t)HD * 4);
    float* bnsum = (float*)nxt((size_t)HD * 4);  // + bnsumsq contiguous
    float* bnsumsq = (float*)nxt((size_t)HD * 4);
    float* bnscale = (float*)nxt((size_t)HD * 4);
    float* bnshift = (float*)nxt((size_t)HD * 4);
    float* M1nat = (float*)nxt((size_t)HD * HD * 4);
    float* bvec = (float*)nxt((size_t)HD * 4);
    float* h = (float*)nxt((size_t)N * HD * 4);
    float* hn = (float*)nxt((size_t)N * HD * 4);
    float* qb = (float*)nxt((size_t)N * HD * 4);
    // bf16 activations
    bf16_t* hb = (bf16_t*)nxt((size_t)N * HD * 2);
    bf16_t* p1b = (bf16_t*)nxt((size_t)N * HD * 2);
    bf16_t* p2b = (bf16_t*)nxt((size_t)N * HD * 2);
    bf16_t* p3b = (bf16_t*)nxt((size_t)N * HD * 2);
    bf16_t* knb = (bf16_t*)nxt((size_t)N * HD * 2);
    bf16_t* qnb = (bf16_t*)nxt((size_t)N * HD * 2);
    // fragment-packed bf16 weights
    bf16_t* Wp_in = (bf16_t*)nxt((size_t)8 * 4 * 64 * 8 * 2);
    bf16_t* Wp_q = (bf16_t*)nxt((size_t)2 * 8 * 4 * 64 * 8 * 2);
    bf16_t* Wp_k = (bf16_t*)nxt((size_t)2 * 8 * 4 * 64 * 8 * 2);
    bf16_t* Wp_fc = (bf16_t*)nxt((size_t)2 * 8 * 20 * 64 * 8 * 2);
    bf16_t* WpM1 = (bf16_t*)nxt((size_t)8 * 4 * 64 * 8 * 2);

    const int GB = (N + 63) / 64;
    const int QSZ = HD * HD;
    const int FSZ = 8 * 20 * 64 * 8;

    // ---- CSR build ----
    hipMemsetAsync(counts, 0, (size_t)N * 4, stream);
    count_edges<<<(E + 255) / 256, 256, 0, stream>>>(colp, counts, E);
    dis_kernel<<<(N + 255) / 256, 256, 0, stream>>>(counts, dis, N);
    scan_kernel<<<1, 1024, 0, stream>>>(counts, offsets, N);
    hipMemsetAsync(cursor, 0, (size_t)N * 4, stream);
    scatter_edges<<<(E + 255) / 256, 256, 0, stream>>>(rowp, colp, dis, offsets, cursor,
                                                       row_sorted, ew_sorted, E);

    // ---- weight packing ----
    wcvt_frag<<<8, 256, 0, stream>>>(W_in, Wp_in, 4);
    wcvt_frag<<<8, 256, 0, stream>>>(Wq, Wp_q, 4);
    wcvt_frag<<<8, 256, 0, stream>>>(Wq + QSZ, Wp_q + QSZ, 4);
    wcvt_frag<<<8, 256, 0, stream>>>(Wk, Wp_k, 4);
    wcvt_frag<<<8, 256, 0, stream>>>(Wk + QSZ, Wp_k + QSZ, 4);
    wcvt_frag<<<40, 256, 0, stream>>>(Wfc, Wp_fc, 20);
    wcvt_frag<<<40, 256, 0, stream>>>(Wfc + 640 * HD, Wp_fc + FSZ, 20);

    // ---- input layer ----
    gemm128s<float, false><<<GB, 256, 0, stream>>>(x, Wp_in, b_in, hn, nullptr, N);
    hipMemsetAsync(bnsum, 0, 1024, stream);
    bn_stats<<<400, 256, 0, stream>>>(hn, bnsum, bnsumsq, N);
    bn_finalize<<<1, 128, 0, stream>>>(bnsum, bnsumsq, bn_g, bn_b, bnscale, bnshift, N);
    bn_apply<<<(N * 32 + 255) / 256, 256, 0, stream>>>((const float4*)hn, (float4*)h, hb,
                                                       bnscale, bnshift, N * 32);

    for (int i = 0; i < 2; i++) {
        const float* bq_i = bq + (size_t)i * HD;
        const float* bk_i = bk + (size_t)i * HD;
        const float* bfc_i = bfc + (size_t)i * HD;
        const float* Wfc_i = Wfc + (size_t)i * 640 * HD;  // rows 0..127 = W0
        bf16_t* Wp_q_i = Wp_q + (size_t)i * QSZ;
        bf16_t* Wp_k_i = Wp_k + (size_t)i * QSZ;
        bf16_t* Wp_fc_i = Wp_fc + (size_t)i * FSZ;

        // K-hop diffusion (bf16)
        prop_b<<<N, 128, 0, stream>>>(offsets, row_sorted, ew_sorted, hb, p1b);
        prop_b<<<N, 128, 0, stream>>>(offsets, row_sorted, ew_sorted, p1b, p2b);
        prop_b<<<N, 128, 0, stream>>>(offsets, row_sorted, ew_sorted, p2b, p3b);

        // attention: qn (fp32 + bf16, normalized), kn (bf16, normalized)
        gemm128s<bf16_t, true><<<GB, 256, 0, stream>>>(hb, Wp_q_i, bq_i, qb, qnb, N);
        gemm128s<bf16_t, true><<<GB, 256, 0, stream>>>(hb, Wp_k_i, bk_i, nullptr, knb, N);
        hipMemsetAsync(kvs, 0, 66560, stream);  // kvs + ksum + vsum
        kvs_mfma<<<256, 256, 0, stream>>>(knb, hb, kvs, ksum, vsum, N);
        den_kernel<<<(N + 3) / 4, 256, 0, stream>>>(qb, ksum, den, N);
        // fold x1 @ W0 into qn @ M1
        m1_kernel<<<64, 256, 0, stream>>>(kvs, Wfc_i, M1nat);
        wcvt_frag<<<8, 256, 0, stream>>>(M1nat, WpM1, 4);
        bvec_kernel<<<1, 128, 0, stream>>>(vsum, Wfc_i, bvec);

        // z = (qn@M1 + bvec)/den + [h,p1,p2,p3]@W[128:] + bfc + h
        gemm_fc<<<GB, 256, 0, stream>>>(qnb, hb, p1b, p2b, p3b, WpM1, Wp_fc_i, bvec, bfc_i, den,
                                        h, hn, N);
        hipMemsetAsync(bnsum, 0, 1024, stream);
        bn_stats<<<400, 256, 0, stream>>>(hn, bnsum, bnsumsq, N);
        bn_finalize<<<1, 128, 0, stream>>>(bnsum, bnsumsq, bn_g + (size_t)(i + 1) * HD,
                                           bn_b + (size_t)(i + 1) * HD, bnscale, bnshift, N);
        bn_apply<<<(N * 32 + 255) / 256, 256, 0, stream>>>((const float4*)hn, (float4*)h, hb,
                                                           bnscale, bnshift, N * 32);
    }

    out_gemm<<<(N * 40 + 255) / 256, 256, 0, stream>>>(h, W_out, b_out, out, N);
}

// Round 5
// 865.564 us; speedup vs baseline: 2.3564x; 1.1147x over previous
//
#include <hip/hip_runtime.h>
#include <hip/hip_bf16.h>
#include <math.h>

#define NN 50000
#define NE 800000
#define HD 128
#define EPS_BN 1e-5f

typedef __bf16 bf16_t;
typedef bf16_t bf16x8 __attribute__((ext_vector_type(8)));
typedef bf16_t bf16x4 __attribute__((ext_vector_type(4)));
typedef float f32x4 __attribute__((ext_vector_type(4)));

// ---------------- CSR build ----------------
__global__ void count_edges(const int* __restrict__ col, int* __restrict__ counts, int E) {
    int e = blockIdx.x * 256 + threadIdx.x;
    if (e >= E) return;
    atomicAdd(&counts[col[e]], 1);
}

__global__ void dis_kernel(const int* __restrict__ counts, float* __restrict__ dis, int N) {
    int i = blockIdx.x * 256 + threadIdx.x;
    if (i >= N) return;
    int c = counts[i];
    dis[i] = (c > 0) ? rsqrtf((float)c) : 0.0f;
}

__global__ __launch_bounds__(1024) void scan_kernel(const int* __restrict__ counts,
                                                    int* __restrict__ offsets, int n) {
    __shared__ int wsum[16];
    int tid = threadIdx.x;
    int lane = tid & 63;
    int w = tid >> 6;
    int carry = 0;
    for (int base = 0; base < n; base += 1024) {
        int i = base + tid;
        int v = (i < n) ? counts[i] : 0;
        int x = v;
        #pragma unroll
        for (int o = 1; o < 64; o <<= 1) {
            int t = __shfl_up(x, o, 64);
            if (lane >= o) x += t;
        }
        if (lane == 63) wsum[w] = x;
        __syncthreads();
        if (w == 0 && lane < 16) {
            int y = wsum[lane];
            #pragma unroll
            for (int o = 1; o < 16; o <<= 1) {
                int t = __shfl_up(y, o, 64);
                if (lane >= o) y += t;
            }
            wsum[lane] = y;
        }
        __syncthreads();
        int wpre = (w > 0) ? wsum[w - 1] : 0;
        int incl = carry + wpre + x;
        if (i < n) offsets[i] = incl - v;  // exclusive
        carry += wsum[15];
        __syncthreads();
    }
    if (tid == 0) offsets[n] = carry;
}

__global__ void scatter_edges(const int* __restrict__ row, const int* __restrict__ col,
                              const float* __restrict__ dis, const int* __restrict__ offsets,
                              int* __restrict__ cursor, int* __restrict__ row_sorted,
                              float* __restrict__ ew_sorted, int E) {
    int e = blockIdx.x * 256 + threadIdx.x;
    if (e >= E) return;
    int c = col[e], r = row[e];
    int pos = offsets[c] + atomicAdd(&cursor[c], 1);
    row_sorted[pos] = r;
    ew_sorted[pos] = dis[c] * dis[r];
}

// ---------------- Graph propagation (CSR gather, bf16 rows, fp32 accum) ----------------
__global__ __launch_bounds__(128) void prop_b(const int* __restrict__ offsets,
                                              const int* __restrict__ row_sorted,
                                              const float* __restrict__ ew_sorted,
                                              const bf16_t* __restrict__ in,
                                              bf16_t* __restrict__ out) {
    int c = blockIdx.x;
    int ch = threadIdx.x;
    int s = offsets[c], e = offsets[c + 1];
    float acc = 0.0f;
    int i = s;
    for (; i + 3 < e; i += 4) {
        int r0 = row_sorted[i], r1 = row_sorted[i + 1];
        int r2 = row_sorted[i + 2], r3 = row_sorted[i + 3];
        float w0 = ew_sorted[i], w1 = ew_sorted[i + 1];
        float w2 = ew_sorted[i + 2], w3 = ew_sorted[i + 3];
        float a0 = (float)in[((size_t)r0 << 7) + ch];
        float a1 = (float)in[((size_t)r1 << 7) + ch];
        float a2 = (float)in[((size_t)r2 << 7) + ch];
        float a3 = (float)in[((size_t)r3 << 7) + ch];
        acc += w0 * a0 + w1 * a1 + w2 * a2 + w3 * a3;
    }
    for (; i < e; i++)
        acc += ew_sorted[i] * (float)in[((size_t)row_sorted[i] << 7) + ch];
    out[((size_t)c << 7) + ch] = (bf16_t)acc;
}

// ---------------- Weight packing: fragment order ----------------
__global__ void wcvt_frag(const float* __restrict__ W, bf16_t* __restrict__ Wp, int nkc) {
    int p = blockIdx.x * 256 + threadIdx.x;
    if (p >= 8 * nkc * 64) return;
    int lane = p & 63;
    int tk = p >> 6;
    int kc = tk % nkc;
    int t = tk / nkc;
    int n = t * 16 + (lane & 15);
    int k0 = kc * 32 + (lane >> 4) * 8;
    bf16x8 f;
    #pragma unroll
    for (int j = 0; j < 8; j++) f[j] = (bf16_t)W[(size_t)(k0 + j) * 128 + n];
    *(bf16x8*)(Wp + (size_t)p * 8) = f;
}

// pack W_out [128][40] into 3 tiles (pad to 48 cols)
__global__ void wcvt_out(const float* __restrict__ W, bf16_t* __restrict__ Wp) {
    int p = blockIdx.x * 256 + threadIdx.x;
    if (p >= 3 * 4 * 64) return;
    int lane = p & 63;
    int tk = p >> 6;
    int kc = tk & 3;
    int t = tk >> 2;
    int n = t * 16 + (lane & 15);
    int k0 = kc * 32 + (lane >> 4) * 8;
    bf16x8 f;
    #pragma unroll
    for (int j = 0; j < 8; j++) f[j] = (n < 40) ? (bf16_t)W[(size_t)(k0 + j) * 40 + n] : (bf16_t)0.0f;
    *(bf16x8*)(Wp + (size_t)p * 8) = f;
}

// ---------------- A-fragment loaders ----------------
__device__ inline bf16x8 loadA(const float* ap) {
    float4 a0 = *(const float4*)ap;
    float4 a1 = *(const float4*)(ap + 4);
    bf16x8 f;
    f[0] = (bf16_t)a0.x; f[1] = (bf16_t)a0.y; f[2] = (bf16_t)a0.z; f[3] = (bf16_t)a0.w;
    f[4] = (bf16_t)a1.x; f[5] = (bf16_t)a1.y; f[6] = (bf16_t)a1.z; f[7] = (bf16_t)a1.w;
    return f;
}
__device__ inline bf16x8 loadA(const bf16_t* ap) { return *(const bf16x8*)ap; }

// ---------------- MFMA GEMM (K=128) with optional norm / den / bn-stats fusion ----------------
template <typename T, bool NORM>
__global__ __launch_bounds__(256) void gemm128s(const T* __restrict__ A,
                                                const bf16_t* __restrict__ Wp,
                                                const float* __restrict__ bias,
                                                const float* __restrict__ ksum_p,
                                                float* __restrict__ den_out,
                                                float* __restrict__ sums,
                                                float* __restrict__ sumsq,
                                                float* __restrict__ out,
                                                bf16_t* __restrict__ outb, int N) {
    __shared__ float lsum[128], lsq[128];
    int tid = threadIdx.x;
    int wave = tid >> 6;
    int lane = tid & 63;
    int quad = lane >> 4;
    int l16 = lane & 15;
    int m0 = blockIdx.x * 64 + wave * 16;
    int arow = m0 + l16;

    f32x4 acc[8] = {};
    #pragma unroll
    for (int kc = 0; kc < 4; kc++) {
        bf16x8 afrag = {};
        if (arow < N) afrag = loadA(A + ((size_t)arow << 7) + kc * 32 + quad * 8);
        #pragma unroll
        for (int t = 0; t < 8; t++) {
            const bf16_t* bp = Wp + (size_t)(((t * 4 + kc) * 64) + lane) * 8;
            acc[t] = __builtin_amdgcn_mfma_f32_16x16x32_bf16(afrag, *(const bf16x8*)bp, acc[t],
                                                             0, 0, 0);
        }
    }
    float vals[8][4];
    #pragma unroll
    for (int t = 0; t < 8; t++) {
        float b = bias ? bias[t * 16 + l16] : 0.0f;
        #pragma unroll
        for (int r = 0; r < 4; r++) vals[t][r] = acc[t][r] + b;
    }
    if (NORM) {
        #pragma unroll
        for (int r = 0; r < 4; r++) {
            float p = 0.0f;
            #pragma unroll
            for (int t = 0; t < 8; t++) p += vals[t][r] * vals[t][r];
            p += __shfl_xor(p, 1);
            p += __shfl_xor(p, 2);
            p += __shfl_xor(p, 4);
            p += __shfl_xor(p, 8);
            float inv = rsqrtf(p);
            #pragma unroll
            for (int t = 0; t < 8; t++) vals[t][r] *= inv;
        }
    }
    if (ksum_p) {  // fused den = qn . ksum + N
        float kv[8];
        #pragma unroll
        for (int t = 0; t < 8; t++) kv[t] = ksum_p[t * 16 + l16];
        #pragma unroll
        for (int r = 0; r < 4; r++) {
            float dp = 0.0f;
            #pragma unroll
            for (int t = 0; t < 8; t++) dp += vals[t][r] * kv[t];
            dp += __shfl_xor(dp, 1);
            dp += __shfl_xor(dp, 2);
            dp += __shfl_xor(dp, 4);
            dp += __shfl_xor(dp, 8);
            int rr = m0 + quad * 4 + r;
            if (l16 == 0 && rr < N) den_out[rr] = dp + (float)NN;
        }
    }
    #pragma unroll
    for (int r = 0; r < 4; r++) {
        int rr = m0 + quad * 4 + r;
        if (rr >= N) continue;
        #pragma unroll
        for (int t = 0; t < 8; t++) {
            int c = t * 16 + l16;
            float v = vals[t][r];
            if (out) out[((size_t)rr << 7) + c] = v;
            if (outb) outb[((size_t)rr << 7) + c] = (bf16_t)v;
        }
    }
    if (sums) {  // fused BN stats
        if (tid < 128) { lsum[tid] = 0.0f; lsq[tid] = 0.0f; }
        __syncthreads();
        float sp[8] = {}, qp[8] = {};
        #pragma unroll
        for (int r = 0; r < 4; r++) {
            int rr = m0 + quad * 4 + r;
            if (rr >= N) continue;
            #pragma unroll
            for (int t = 0; t < 8; t++) {
                float v = vals[t][r];
                sp[t] += v;
                qp[t] += v * v;
            }
        }
        #pragma unroll
        for (int t = 0; t < 8; t++) {
            sp[t] += __shfl_xor(sp[t], 16);
            sp[t] += __shfl_xor(sp[t], 32);
            qp[t] += __shfl_xor(qp[t], 16);
            qp[t] += __shfl_xor(qp[t], 32);
        }
        if (quad == 0) {
            #pragma unroll
            for (int t = 0; t < 8; t++) {
                atomicAdd(&lsum[t * 16 + l16], sp[t]);
                atomicAdd(&lsq[t * 16 + l16], qp[t]);
            }
        }
        __syncthreads();
        if (tid < 128) {
            atomicAdd(&sums[tid], lsum[tid]);
            atomicAdd(&sumsq[tid], lsq[tid]);
        }
    }
}

// ---------------- fc GEMM with folded attention + fused BN stats ----------------
__global__ __launch_bounds__(256) void gemm_fc(
    const bf16_t* __restrict__ qn, const bf16_t* __restrict__ s1, const bf16_t* __restrict__ s2,
    const bf16_t* __restrict__ s3, const bf16_t* __restrict__ s4,
    const bf16_t* __restrict__ WpM1, const bf16_t* __restrict__ Wp,
    const float* __restrict__ bvec, const float* __restrict__ bfc,
    const float* __restrict__ den, const float* __restrict__ res,
    float* __restrict__ sums, float* __restrict__ sumsq,
    float* __restrict__ out, int N) {
    __shared__ float lsum[128], lsq[128];
    const bf16_t* srcs[4] = {s1, s2, s3, s4};
    int tid = threadIdx.x;
    int wave = tid >> 6;
    int lane = tid & 63;
    int quad = lane >> 4;
    int l16 = lane & 15;
    int m0 = blockIdx.x * 64 + wave * 16;
    int arow = m0 + l16;

    f32x4 accA[8] = {};
    f32x4 accB[8] = {};
    #pragma unroll
    for (int kc = 0; kc < 4; kc++) {
        bf16x8 afrag = {};
        if (arow < N) afrag = *(const bf16x8*)(qn + ((size_t)arow << 7) + kc * 32 + quad * 8);
        #pragma unroll
        for (int t = 0; t < 8; t++) {
            const bf16_t* bp = WpM1 + (size_t)(((t * 4 + kc) * 64) + lane) * 8;
            accA[t] = __builtin_amdgcn_mfma_f32_16x16x32_bf16(afrag, *(const bf16x8*)bp, accA[t],
                                                              0, 0, 0);
        }
    }
    #pragma unroll
    for (int s = 0; s < 4; s++) {
        const bf16_t* As = srcs[s];
        #pragma unroll
        for (int k2 = 0; k2 < 4; k2++) {
            bf16x8 afrag = {};
            if (arow < N) afrag = *(const bf16x8*)(As + ((size_t)arow << 7) + k2 * 32 + quad * 8);
            int kcidx = (s + 1) * 4 + k2;
            #pragma unroll
            for (int t = 0; t < 8; t++) {
                const bf16_t* bp = Wp + (size_t)(((t * 20 + kcidx) * 64) + lane) * 8;
                accB[t] = __builtin_amdgcn_mfma_f32_16x16x32_bf16(afrag, *(const bf16x8*)bp,
                                                                  accB[t], 0, 0, 0);
            }
        }
    }
    float vals[8][4];
    #pragma unroll
    for (int r = 0; r < 4; r++) {
        int rr = m0 + quad * 4 + r;
        if (rr >= N) continue;
        float dinv = 1.0f / den[rr];
        #pragma unroll
        for (int t = 0; t < 8; t++) {
            int c = t * 16 + l16;
            float v = (accA[t][r] + bvec[c]) * dinv + accB[t][r] + bfc[c] +
                      res[((size_t)rr << 7) + c];
            vals[t][r] = v;
            out[((size_t)rr << 7) + c] = v;
        }
    }
    // fused BN stats
    if (tid < 128) { lsum[tid] = 0.0f; lsq[tid] = 0.0f; }
    __syncthreads();
    float sp[8] = {}, qp[8] = {};
    #pragma unroll
    for (int r = 0; r < 4; r++) {
        int rr = m0 + quad * 4 + r;
        if (rr >= N) continue;
        #pragma unroll
        for (int t = 0; t < 8; t++) {
            float v = vals[t][r];
            sp[t] += v;
            qp[t] += v * v;
        }
    }
    #pragma unroll
    for (int t = 0; t < 8; t++) {
        sp[t] += __shfl_xor(sp[t], 16);
        sp[t] += __shfl_xor(sp[t], 32);
        qp[t] += __shfl_xor(qp[t], 16);
        qp[t] += __shfl_xor(qp[t], 32);
    }
    if (quad == 0) {
        #pragma unroll
        for (int t = 0; t < 8; t++) {
            atomicAdd(&lsum[t * 16 + l16], sp[t]);
            atomicAdd(&lsq[t * 16 + l16], qp[t]);
        }
    }
    __syncthreads();
    if (tid < 128) {
        atomicAdd(&sums[tid], lsum[tid]);
        atomicAdd(&sumsq[tid], lsq[tid]);
    }
}

// ---------------- out GEMM via MFMA: out[N,40] = hb @ W_out + b_out ----------------
__global__ __launch_bounds__(256) void out_mfma(const bf16_t* __restrict__ hb,
                                                const bf16_t* __restrict__ Wp,
                                                const float* __restrict__ bias,
                                                float* __restrict__ out, int N) {
    int wave = threadIdx.x >> 6;
    int lane = threadIdx.x & 63;
    int quad = lane >> 4;
    int l16 = lane & 15;
    int m0 = blockIdx.x * 64 + wave * 16;
    int arow = m0 + l16;

    f32x4 acc[3] = {};
    #pragma unroll
    for (int kc = 0; kc < 4; kc++) {
        bf16x8 afrag = {};
        if (arow < N) afrag = *(const bf16x8*)(hb + ((size_t)arow << 7) + kc * 32 + quad * 8);
        #pragma unroll
        for (int t = 0; t < 3; t++) {
            const bf16_t* bp = Wp + (size_t)(((t * 4 + kc) * 64) + lane) * 8;
            acc[t] = __builtin_amdgcn_mfma_f32_16x16x32_bf16(afrag, *(const bf16x8*)bp, acc[t],
                                                             0, 0, 0);
        }
    }
    #pragma unroll
    for (int r = 0; r < 4; r++) {
        int rr = m0 + quad * 4 + r;
        if (rr >= N) continue;
        #pragma unroll
        for (int t = 0; t < 3; t++) {
            int c = t * 16 + l16;
            if (c < 40) out[(size_t)rr * 40 + c] = acc[t][r] + bias[c];
        }
    }
}

// ---------------- kvs via MFMA ----------------
__global__ __launch_bounds__(256) void kvs_mfma(const bf16_t* __restrict__ kn,
                                                const bf16_t* __restrict__ v,
                                                float* __restrict__ kvs,
                                                float* __restrict__ ksum,
                                                float* __restrict__ vsum, int N) {
    __shared__ bf16_t Lk[32][132];
    __shared__ bf16_t Lv[32][132];
    __shared__ float lred[256];
    int t = threadIdx.x;
    int wave = t >> 6, lane = t & 63, quad = lane >> 4, l16 = lane & 15;
    int tr = t >> 4, tc = (t & 15) * 8;
    int mbase = wave * 32;
    f32x4 acc[2][8] = {};
    float ks[8] = {}, vs[8] = {};
    for (int base = blockIdx.x * 32; base < N; base += gridDim.x * 32) {
        __syncthreads();
        #pragma unroll
        for (int hh = 0; hh < 2; hh++) {
            int r = hh * 16 + tr;
            int rowi = base + r;
            bf16x8 ck = {}, cv = {};
            if (rowi < N) {
                ck = *(const bf16x8*)(kn + ((size_t)rowi << 7) + tc);
                cv = *(const bf16x8*)(v + ((size_t)rowi << 7) + tc);
            }
            bf16x4 klo, khi, vlo, vhi;
            #pragma unroll
            for (int j = 0; j < 4; j++) {
                klo[j] = ck[j]; khi[j] = ck[j + 4];
                vlo[j] = cv[j]; vhi[j] = cv[j + 4];
                ks[j] += (float)ck[j]; ks[j + 4] += (float)ck[j + 4];
                vs[j] += (float)cv[j]; vs[j + 4] += (float)cv[j + 4];
            }
            *(bf16x4*)&Lk[r][tc] = klo;
            *(bf16x4*)&Lk[r][tc + 4] = khi;
            *(bf16x4*)&Lv[r][tc] = vlo;
            *(bf16x4*)&Lv[r][tc + 4] = vhi;
        }
        __syncthreads();
        bf16x8 af[2], bfr[8];
        #pragma unroll
        for (int mt = 0; mt < 2; mt++)
            #pragma unroll
            for (int j = 0; j < 8; j++) af[mt][j] = Lk[quad * 8 + j][mbase + mt * 16 + l16];
        #pragma unroll
        for (int tt = 0; tt < 8; tt++)
            #pragma unroll
            for (int j = 0; j < 8; j++) bfr[tt][j] = Lv[quad * 8 + j][tt * 16 + l16];
        #pragma unroll
        for (int mt = 0; mt < 2; mt++)
            #pragma unroll
            for (int tt = 0; tt < 8; tt++)
                acc[mt][tt] = __builtin_amdgcn_mfma_f32_16x16x32_bf16(af[mt], bfr[tt],
                                                                      acc[mt][tt], 0, 0, 0);
    }
    #pragma unroll
    for (int mt = 0; mt < 2; mt++)
        #pragma unroll
        for (int tt = 0; tt < 8; tt++)
            #pragma unroll
            for (int r = 0; r < 4; r++) {
                int m = mbase + mt * 16 + quad * 4 + r;
                int d = tt * 16 + l16;
                atomicAdd(&kvs[m * HD + d], acc[mt][tt][r]);
            }
    lred[t] = 0.0f;
    __syncthreads();
    #pragma unroll
    for (int j = 0; j < 8; j++) {
        atomicAdd(&lred[tc + j], ks[j]);
        atomicAdd(&lred[128 + tc + j], vs[j]);
    }
    __syncthreads();
    if (t < 128) {
        atomicAdd(&ksum[t], lred[t]);
        atomicAdd(&vsum[t], lred[t + 128]);
    }
}

// ---------------- M1 = kvs @ W0, bvec = vsum @ W0 ----------------
__global__ void m1_kernel(const float* __restrict__ kvs, const float* __restrict__ W0,
                          float* __restrict__ M1) {
    int idx = blockIdx.x * 256 + threadIdx.x;
    int m = idx >> 7;
    int c = idx & 127;
    float acc = 0.0f;
    for (int d = 0; d < 128; d += 4) {
        float4 k4 = *(const float4*)(kvs + m * 128 + d);
        acc += k4.x * W0[(d + 0) * 128 + c] + k4.y * W0[(d + 1) * 128 + c] +
               k4.z * W0[(d + 2) * 128 + c] + k4.w * W0[(d + 3) * 128 + c];
    }
    M1[idx] = acc;
}

__global__ void bvec_kernel(const float* __restrict__ vsum, const float* __restrict__ W0,
                            float* __restrict__ bvec) {
    int c = threadIdx.x;
    float acc = 0.0f;
    for (int d = 0; d < 128; d++) acc += vsum[d] * W0[d * 128 + c];
    bvec[c] = acc;
}

// ---------------- BatchNorm finalize + apply ----------------
__global__ void bn_finalize(const float* __restrict__ sums, const float* __restrict__ sumsq,
                            const float* __restrict__ g, const float* __restrict__ b,
                            float* __restrict__ scale, float* __restrict__ shift, int N) {
    int ch = threadIdx.x;
    float m = sums[ch] / (float)N;
    float var = sumsq[ch] / (float)N - m * m;
    float sc = g[ch] * rsqrtf(var + EPS_BN);
    scale[ch] = sc;
    shift[ch] = b[ch] - m * sc;
}

__global__ void bn_apply(const float4* __restrict__ z, float4* __restrict__ h,
                         bf16_t* __restrict__ hb, const float* __restrict__ scale,
                         const float* __restrict__ shift, int n4) {
    int i = blockIdx.x * blockDim.x + threadIdx.x;
    if (i >= n4) return;
    int c4 = i & 31;
    float4 zv = z[i];
    float4 sc = ((const float4*)scale)[c4];
    float4 sh = ((const float4*)shift)[c4];
    float4 hv;
    hv.x = fmaxf(zv.x * sc.x + sh.x, 0.0f);
    hv.y = fmaxf(zv.y * sc.y + sh.y, 0.0f);
    hv.z = fmaxf(zv.z * sc.z + sh.z, 0.0f);
    hv.w = fmaxf(zv.w * sc.w + sh.w, 0.0f);
    h[i] = hv;
    bf16x4 hb4;
    hb4[0] = (bf16_t)hv.x; hb4[1] = (bf16_t)hv.y; hb4[2] = (bf16_t)hv.z; hb4[3] = (bf16_t)hv.w;
    *(bf16x4*)(hb + (size_t)i * 4) = hb4;
}

extern "C" void kernel_launch(void* const* d_in, const int* in_sizes, int n_in,
                              void* d_out, int out_size, void* d_ws, size_t ws_size,
                              hipStream_t stream) {
    const float* x = (const float*)d_in[0];
    const int* eidx = (const int*)d_in[1];
    const float* W_in = (const float*)d_in[2];
    const float* b_in = (const float*)d_in[3];
    const float* Wq = (const float*)d_in[4];
    const float* bq = (const float*)d_in[5];
    const float* Wk = (const float*)d_in[6];
    const float* bk = (const float*)d_in[7];
    const float* Wfc = (const float*)d_in[8];
    const float* bfc = (const float*)d_in[9];
    const float* W_out = (const float*)d_in[10];
    const float* b_out = (const float*)d_in[11];
    const float* bn_g = (const float*)d_in[12];
    const float* bn_b = (const float*)d_in[13];
    float* out = (float*)d_out;

    const int N = NN, E = NE;
    const int* rowp = eidx;
    const int* colp = eidx + E;

    char* ws = (char*)d_ws;
    size_t off = 0;
    auto nxt = [&](size_t bytes) -> void* {
        void* p = ws + off;
        off += (bytes + 255) & ~(size_t)255;
        return p;
    };
    int* counts = (int*)nxt((size_t)N * 4);
    int* offsets = (int*)nxt((size_t)(N + 1) * 4);
    int* cursor = (int*)nxt((size_t)N * 4);
    int* row_sorted = (int*)nxt((size_t)E * 4);
    float* ew_sorted = (float*)nxt((size_t)E * 4);
    float* dis = (float*)nxt((size_t)N * 4);
    float* den = (float*)nxt((size_t)N * 4);
    float* kvs = (float*)nxt((size_t)HD * HD * 4);  // + ksum + vsum contiguous
    float* ksum = (float*)nxt((size_t)HD * 4);
    float* vsum = (float*)nxt((size_t)HD * 4);
    float* bnsum = (float*)nxt((size_t)HD * 4);  // + bnsumsq contiguous
    float* bnsumsq = (float*)nxt((size_t)HD * 4);
    float* bnscale = (float*)nxt((size_t)HD * 4);
    float* bnshift = (float*)nxt((size_t)HD * 4);
    float* M1nat = (float*)nxt((size_t)HD * HD * 4);
    float* bvec = (float*)nxt((size_t)HD * 4);
    float* h = (float*)nxt((size_t)N * HD * 4);
    float* hn = (float*)nxt((size_t)N * HD * 4);
    // bf16 activations
    bf16_t* hb = (bf16_t*)nxt((size_t)N * HD * 2);
    bf16_t* p1b = (bf16_t*)nxt((size_t)N * HD * 2);
    bf16_t* p2b = (bf16_t*)nxt((size_t)N * HD * 2);
    bf16_t* p3b = (bf16_t*)nxt((size_t)N * HD * 2);
    bf16_t* knb = (bf16_t*)nxt((size_t)N * HD * 2);
    bf16_t* qnb = (bf16_t*)nxt((size_t)N * HD * 2);
    // fragment-packed bf16 weights
    bf16_t* Wp_in = (bf16_t*)nxt((size_t)8 * 4 * 64 * 8 * 2);
    bf16_t* Wp_q = (bf16_t*)nxt((size_t)2 * 8 * 4 * 64 * 8 * 2);
    bf16_t* Wp_k = (bf16_t*)nxt((size_t)2 * 8 * 4 * 64 * 8 * 2);
    bf16_t* Wp_fc = (bf16_t*)nxt((size_t)2 * 8 * 20 * 64 * 8 * 2);
    bf16_t* WpM1 = (bf16_t*)nxt((size_t)8 * 4 * 64 * 8 * 2);
    bf16_t* Wp_out = (bf16_t*)nxt((size_t)3 * 4 * 64 * 8 * 2);

    const int GB = (N + 63) / 64;
    const int QSZ = HD * HD;
    const int FSZ = 8 * 20 * 64 * 8;

    // ---- CSR build ----
    hipMemsetAsync(counts, 0, (size_t)N * 4, stream);
    count_edges<<<(E + 255) / 256, 256, 0, stream>>>(colp, counts, E);
    dis_kernel<<<(N + 255) / 256, 256, 0, stream>>>(counts, dis, N);
    scan_kernel<<<1, 1024, 0, stream>>>(counts, offsets, N);
    hipMemsetAsync(cursor, 0, (size_t)N * 4, stream);
    scatter_edges<<<(E + 255) / 256, 256, 0, stream>>>(rowp, colp, dis, offsets, cursor,
                                                       row_sorted, ew_sorted, E);

    // ---- weight packing ----
    wcvt_frag<<<8, 256, 0, stream>>>(W_in, Wp_in, 4);
    wcvt_frag<<<8, 256, 0, stream>>>(Wq, Wp_q, 4);
    wcvt_frag<<<8, 256, 0, stream>>>(Wq + QSZ, Wp_q + QSZ, 4);
    wcvt_frag<<<8, 256, 0, stream>>>(Wk, Wp_k, 4);
    wcvt_frag<<<8, 256, 0, stream>>>(Wk + QSZ, Wp_k + QSZ, 4);
    wcvt_frag<<<40, 256, 0, stream>>>(Wfc, Wp_fc, 20);
    wcvt_frag<<<40, 256, 0, stream>>>(Wfc + 640 * HD, Wp_fc + FSZ, 20);
    wcvt_out<<<3, 256, 0, stream>>>(W_out, Wp_out);

    // ---- input layer (fused BN stats) ----
    hipMemsetAsync(bnsum, 0, 1024, stream);
    gemm128s<float, false><<<GB, 256, 0, stream>>>(x, Wp_in, b_in, nullptr, nullptr, bnsum,
                                                   bnsumsq, hn, nullptr, N);
    bn_finalize<<<1, 128, 0, stream>>>(bnsum, bnsumsq, bn_g, bn_b, bnscale, bnshift, N);
    bn_apply<<<(N * 32 + 255) / 256, 256, 0, stream>>>((const float4*)hn, (float4*)h, hb,
                                                       bnscale, bnshift, N * 32);

    for (int i = 0; i < 2; i++) {
        const float* bq_i = bq + (size_t)i * HD;
        const float* bk_i = bk + (size_t)i * HD;
        const float* bfc_i = bfc + (size_t)i * HD;
        const float* Wfc_i = Wfc + (size_t)i * 640 * HD;  // rows 0..127 = W0
        bf16_t* Wp_q_i = Wp_q + (size_t)i * QSZ;
        bf16_t* Wp_k_i = Wp_k + (size_t)i * QSZ;
        bf16_t* Wp_fc_i = Wp_fc + (size_t)i * FSZ;

        // K-hop diffusion (bf16)
        prop_b<<<N, 128, 0, stream>>>(offsets, row_sorted, ew_sorted, hb, p1b);
        prop_b<<<N, 128, 0, stream>>>(offsets, row_sorted, ew_sorted, p1b, p2b);
        prop_b<<<N, 128, 0, stream>>>(offsets, row_sorted, ew_sorted, p2b, p3b);

        // attention: k first, then kvs, then q (with fused den via ksum)
        gemm128s<bf16_t, true><<<GB, 256, 0, stream>>>(hb, Wp_k_i, bk_i, nullptr, nullptr,
                                                       nullptr, nullptr, nullptr, knb, N);
        hipMemsetAsync(kvs, 0, 66560, stream);  // kvs + ksum + vsum
        kvs_mfma<<<256, 256, 0, stream>>>(knb, hb, kvs, ksum, vsum, N);
        gemm128s<bf16_t, true><<<GB, 256, 0, stream>>>(hb, Wp_q_i, bq_i, ksum, den, nullptr,
                                                       nullptr, nullptr, qnb, N);
        // fold x1 @ W0 into qn @ M1
        m1_kernel<<<64, 256, 0, stream>>>(kvs, Wfc_i, M1nat);
        wcvt_frag<<<8, 256, 0, stream>>>(M1nat, WpM1, 4);
        bvec_kernel<<<1, 128, 0, stream>>>(vsum, Wfc_i, bvec);

        // z = (qn@M1 + bvec)/den + [h,p1,p2,p3]@W[128:] + bfc + h  (fused BN stats)
        hipMemsetAsync(bnsum, 0, 1024, stream);
        gemm_fc<<<GB, 256, 0, stream>>>(qnb, hb, p1b, p2b, p3b, WpM1, Wp_fc_i, bvec, bfc_i, den,
                                        h, bnsum, bnsumsq, hn, N);
        bn_finalize<<<1, 128, 0, stream>>>(bnsum, bnsumsq, bn_g + (size_t)(i + 1) * HD,
                                           bn_b + (size_t)(i + 1) * HD, bnscale, bnshift, N);
        bn_apply<<<(N * 32 + 255) / 256, 256, 0, stream>>>((const float4*)hn, (float4*)h, hb,
                                                           bnscale, bnshift, N * 32);
    }

    out_mfma<<<GB, 256, 0, stream>>>(hb, Wp_out, b_out, out, N);
}